// Round 1
// baseline (1496.042 us; speedup 1.0000x reference)
//
#include <hip/hip_runtime.h>
#include <hip/hip_bf16.h>

// Sizes (fixed by the reference): B=4096, D=1024, H1=2048, H2=1024, C=64, T=20
#define B_   4096
#define D_   1024
#define H1_  2048
#define H2_  1024
#define C_   64

// ---------------------------------------------------------------------------
// Transpose: out[c][r] = in[r][c]   (f32, 32x32 LDS tiles)
// ---------------------------------------------------------------------------
__global__ __launch_bounds__(256) void k_transpose(const float* __restrict__ in,
                                                   float* __restrict__ out,
                                                   int R, int C) {
    __shared__ float t[32][33];
    int c0 = blockIdx.x * 32;
    int r0 = blockIdx.y * 32;
    int lx = threadIdx.x;          // 0..31
    int ly = threadIdx.y;          // 0..7
#pragma unroll
    for (int q = 0; q < 4; ++q) {
        int rr = ly + 8 * q;
        t[rr][lx] = in[(size_t)(r0 + rr) * C + (c0 + lx)];
    }
    __syncthreads();
#pragma unroll
    for (int q = 0; q < 4; ++q) {
        int cc = ly + 8 * q;
        out[(size_t)(c0 + cc) * R + (r0 + lx)] = t[lx][cc];
    }
}

// ---------------------------------------------------------------------------
// Dense f64-accumulate GEMM: m1_0[b][n] = sum_k x[b][k]*W1[n][k] + b1[n]
// x: [4096,1024] f32,  W1: [2048,1024] f32,  m1_0: [4096,2048] f64
// 64x64 tile, BK=16, 256 threads, each thread 4x4 f64 acc.
// ---------------------------------------------------------------------------
#define BM 64
#define BN 64
#define BK 16
__global__ __launch_bounds__(256) void k_gemm1(const float* __restrict__ x,
                                               const float* __restrict__ W1,
                                               const float* __restrict__ b1,
                                               double* __restrict__ m1out) {
    __shared__ double As[BK][BM + 1];   // padded: break bank collisions
    __shared__ double Bs[BK][BN + 1];

    int tid = threadIdx.x;
    int m0 = blockIdx.x * BM;
    int n0 = blockIdx.y * BN;
    int tx = tid & 15;       // 0..15 -> m fragment
    int ty = tid >> 4;       // 0..15 -> n fragment

    int lr = tid >> 2;            // 0..63 : row within tile
    int lk = (tid & 3) * 4;       // 0,4,8,12 : k group (float4)

    double acc[4][4] = {};

    for (int k0 = 0; k0 < D_; k0 += BK) {
        float4 av = *(const float4*)&x [(size_t)(m0 + lr) * D_ + k0 + lk];
        float4 bv = *(const float4*)&W1[(size_t)(n0 + lr) * D_ + k0 + lk];
        __syncthreads();
        As[lk + 0][lr] = (double)av.x;
        As[lk + 1][lr] = (double)av.y;
        As[lk + 2][lr] = (double)av.z;
        As[lk + 3][lr] = (double)av.w;
        Bs[lk + 0][lr] = (double)bv.x;
        Bs[lk + 1][lr] = (double)bv.y;
        Bs[lk + 2][lr] = (double)bv.z;
        Bs[lk + 3][lr] = (double)bv.w;
        __syncthreads();
#pragma unroll
        for (int kk = 0; kk < BK; ++kk) {
            double a[4], b[4];
#pragma unroll
            for (int i = 0; i < 4; ++i) a[i] = As[kk][tx + 16 * i];
#pragma unroll
            for (int j = 0; j < 4; ++j) b[j] = Bs[kk][ty + 16 * j];
#pragma unroll
            for (int i = 0; i < 4; ++i)
#pragma unroll
                for (int j = 0; j < 4; ++j)
                    acc[i][j] += a[i] * b[j];
        }
    }
#pragma unroll
    for (int j = 0; j < 4; ++j) {
        double bj = (double)b1[n0 + ty + 16 * j];
#pragma unroll
        for (int i = 0; i < 4; ++i) {
            m1out[(size_t)(m0 + tx + 16 * i) * H1_ + (n0 + ty + 16 * j)] =
                acc[i][j] + bj;
        }
    }
}

// ---------------------------------------------------------------------------
// Persistent per-sample SNN: one block = one sample, 20 steps in LDS.
// ---------------------------------------------------------------------------
__global__ __launch_bounds__(256) void k_snn(const double* __restrict__ m1_0,
                                             const float* __restrict__ b1,
                                             const float* __restrict__ W1T,  // [D_][H1_]
                                             const float* __restrict__ W2T,  // [H1_][H2_]
                                             const float* __restrict__ b2,
                                             const float* __restrict__ Wo,   // [C_][H2_]
                                             const float* __restrict__ bo,
                                             const int* __restrict__ nsteps_p,
                                             float* __restrict__ out) {
    __shared__ double m1s[H1_];                    // 16 KB
    __shared__ double m2s[H2_];                    // 8 KB
    __shared__ unsigned long long s1bits[H1_ / 64];  // 32 words
    __shared__ unsigned long long s2bits[H2_ / 64];  // 16 words
    __shared__ unsigned short cnt[H2_];            // 2 KB

    int b = blockIdx.x;
    int tid = threadIdx.x;
    int lane = tid & 63;
    int wv = tid >> 6;      // wave id 0..3
    int T = nsteps_p[0];

    for (int j = tid; j < H2_; j += 256) { m2s[j] = 0.0; cnt[j] = 0; }
    if (tid < 16) s2bits[tid] = 0ULL;
    for (int i = tid; i < H1_; i += 256) m1s[i] = m1_0[(size_t)b * H1_ + i];
    __syncthreads();

    for (int t = 0; t < T; ++t) {
        // ---- layer 1: m1 = 0.9*m1_old - r1 + b1 + W1 @ s2_prev ----
        if (t > 0) {
            for (int i = tid; i < H1_; i += 256) {
                double old = m1s[i];
                m1s[i] = 0.9 * old - (old > 1.0 ? 1.0 : 0.0) + (double)b1[i];
            }
            __syncthreads();
            for (int w = 0; w < H2_ / 64; ++w) {
                unsigned long long bits = s2bits[w];
                while (bits) {
                    int k = w * 64 + __builtin_ctzll(bits);
                    bits &= bits - 1;
                    const float* col = &W1T[(size_t)k * H1_];
                    for (int i = tid; i < H1_; i += 256)
                        m1s[i] += (double)col[i];
                }
            }
            __syncthreads();
        }
        // ---- s1 bitmask ----
#pragma unroll
        for (int q = 0; q < 8; ++q) {
            int w = wv * 8 + q;
            unsigned long long bal = __ballot(m1s[w * 64 + lane] > 1.0);
            if (lane == 0) s1bits[w] = bal;
        }
        __syncthreads();
        // ---- layer 2 decay + bias (uses OLD m2) ----
        for (int j = tid; j < H2_; j += 256) {
            double old = m2s[j];
            m2s[j] = 0.9 * old - (old > 1.0 ? 1.0 : 0.0) + (double)b2[j];
        }
        __syncthreads();
        // ---- gather active s1 columns of W2T ----
        for (int w = 0; w < H1_ / 64; ++w) {
            unsigned long long bits = s1bits[w];
            while (bits) {
                int i = w * 64 + __builtin_ctzll(bits);
                bits &= bits - 1;
                const float* col = &W2T[(size_t)i * H2_];
                for (int j = tid; j < H2_; j += 256)
                    m2s[j] += (double)col[j];
            }
        }
        __syncthreads();
        // ---- s2 bitmask + spike counts ----
#pragma unroll
        for (int q = 0; q < 4; ++q) {
            int w = wv * 4 + q;
            unsigned long long bal = __ballot(m2s[w * 64 + lane] > 1.0);
            if (lane == 0) s2bits[w] = bal;
        }
        for (int j = tid; j < H2_; j += 256)
            cnt[j] += (m2s[j] > 1.0) ? 1 : 0;
        __syncthreads();
    }

    // ---- output: out[b][c] = bo[c] + sum_j (cnt[j]/T) * Wo[c][j] ----
    double* pj = m1s;  // reuse (m1 no longer needed)
    for (int j = tid; j < H2_; j += 256) pj[j] = (double)cnt[j] / (double)T;
    __syncthreads();

    int c = tid >> 2, r = tid & 3;
    const float* worow = &Wo[(size_t)c * H2_];
    double acc = 0.0;
    for (int j = r; j < H2_; j += 4)
        acc += pj[j] * (double)worow[j];
    acc += __shfl_xor(acc, 1);
    acc += __shfl_xor(acc, 2);
    if (r == 0)
        out[(size_t)b * C_ + c] = (float)(acc + (double)bo[c]);
}

// ---------------------------------------------------------------------------
extern "C" void kernel_launch(void* const* d_in, const int* in_sizes, int n_in,
                              void* d_out, int out_size, void* d_ws, size_t ws_size,
                              hipStream_t stream) {
    const float* x  = (const float*)d_in[0];   // [4096,1024]
    const float* W1 = (const float*)d_in[1];   // [2048,1024]
    const float* b1 = (const float*)d_in[2];   // [2048]
    const float* W2 = (const float*)d_in[3];   // [1024,2048]
    const float* b2 = (const float*)d_in[4];   // [1024]
    const float* Wo = (const float*)d_in[5];   // [64,1024]
    const float* bo = (const float*)d_in[6];   // [64]
    const int* nst  = (const int*)d_in[7];     // [1] = 20
    float* out = (float*)d_out;

    // workspace layout
    size_t off_m1  = 0;                                   // f64 [4096][2048] = 64 MiB
    size_t off_w1t = off_m1 + (size_t)B_ * H1_ * 8;       // f32 [1024][2048] = 8 MiB
    size_t off_w2t = off_w1t + (size_t)D_ * H1_ * 4;      // f32 [2048][1024] = 8 MiB
    size_t need    = off_w2t + (size_t)H1_ * H2_ * 4;
    if (ws_size < need) return;  // insufficient scratch; fail loudly (zero output)

    double* m1ws = (double*)((char*)d_ws + off_m1);
    float*  W1T  = (float*)((char*)d_ws + off_w1t);
    float*  W2T  = (float*)((char*)d_ws + off_w2t);

    // transposes: W1 [2048,1024] -> W1T [1024][2048]; W2 [1024,2048] -> W2T [2048][1024]
    k_transpose<<<dim3(D_ / 32, H1_ / 32), dim3(32, 8), 0, stream>>>(W1, W1T, H1_, D_);
    k_transpose<<<dim3(H1_ / 32, H2_ / 32), dim3(32, 8), 0, stream>>>(W2, W2T, H2_, H1_);

    // dense f64 GEMM for t=0 layer-1 membrane
    k_gemm1<<<dim3(B_ / BM, H1_ / BN), 256, 0, stream>>>(x, W1, b1, m1ws);

    // persistent per-sample SNN
    k_snn<<<B_, 256, 0, stream>>>(m1ws, b1, W1T, W2T, b2, Wo, bo, nst, out);
}

// Round 2
// 974.622 us; speedup vs baseline: 1.5350x; 1.5350x over previous
//
#include <hip/hip_runtime.h>
#include <hip/hip_bf16.h>

// Sizes (fixed by the reference): B=4096, D=1024, H1=2048, H2=1024, C=64, T=20
#define B_   4096
#define D_   1024
#define H1_  2048
#define H2_  1024
#define C_   64

// ---------------------------------------------------------------------------
// Transpose: out[c][r] = in[r][c]   (f32, 32x32 LDS tiles)
// ---------------------------------------------------------------------------
__global__ __launch_bounds__(256) void k_transpose(const float* __restrict__ in,
                                                   float* __restrict__ out,
                                                   int R, int C) {
    __shared__ float t[32][33];
    int c0 = blockIdx.x * 32;
    int r0 = blockIdx.y * 32;
    int lx = threadIdx.x;          // 0..31
    int ly = threadIdx.y;          // 0..7
#pragma unroll
    for (int q = 0; q < 4; ++q) {
        int rr = ly + 8 * q;
        t[rr][lx] = in[(size_t)(r0 + rr) * C + (c0 + lx)];
    }
    __syncthreads();
#pragma unroll
    for (int q = 0; q < 4; ++q) {
        int cc = ly + 8 * q;
        out[(size_t)(c0 + cc) * R + (r0 + lx)] = t[lx][cc];
    }
}

// ---------------------------------------------------------------------------
// Dense f64-accumulate GEMM: m1_0[b][n] = sum_k x[b][k]*W1[n][k] + b1[n]
// 128x128 tile, BK=8, 256 threads, 8x8 f64 microtile per thread.
// ---------------------------------------------------------------------------
#define BM 128
#define BN 128
#define BK 8
__global__ __launch_bounds__(256) void k_gemm1(const float* __restrict__ x,
                                               const float* __restrict__ W1,
                                               const float* __restrict__ b1,
                                               double* __restrict__ m1out) {
    __shared__ double As[BK][BM + 4];
    __shared__ double Bs[BK][BN + 4];

    int tid = threadIdx.x;
    int m0 = blockIdx.x * BM;
    int n0 = blockIdx.y * BN;
    int tx = tid & 15;       // m fragment: rows tx + 16*i
    int ty = tid >> 4;       // n fragment: cols ty + 16*j

    int lr = tid >> 1;            // 0..127 : row within tile
    int lk = (tid & 1) * 4;       // 0 or 4 : k group (float4)

    double acc[8][8] = {};

    for (int k0 = 0; k0 < D_; k0 += BK) {
        float4 av = *(const float4*)&x [(size_t)(m0 + lr) * D_ + k0 + lk];
        float4 bv = *(const float4*)&W1[(size_t)(n0 + lr) * D_ + k0 + lk];
        __syncthreads();
        As[lk + 0][lr] = (double)av.x;
        As[lk + 1][lr] = (double)av.y;
        As[lk + 2][lr] = (double)av.z;
        As[lk + 3][lr] = (double)av.w;
        Bs[lk + 0][lr] = (double)bv.x;
        Bs[lk + 1][lr] = (double)bv.y;
        Bs[lk + 2][lr] = (double)bv.z;
        Bs[lk + 3][lr] = (double)bv.w;
        __syncthreads();
#pragma unroll
        for (int kk = 0; kk < BK; ++kk) {
            double a[8], b[8];
#pragma unroll
            for (int i = 0; i < 8; ++i) a[i] = As[kk][tx + 16 * i];
#pragma unroll
            for (int j = 0; j < 8; ++j) b[j] = Bs[kk][ty + 16 * j];
#pragma unroll
            for (int i = 0; i < 8; ++i)
#pragma unroll
                for (int j = 0; j < 8; ++j)
                    acc[i][j] += a[i] * b[j];
        }
    }
#pragma unroll
    for (int j = 0; j < 8; ++j) {
        double bj = (double)b1[n0 + ty + 16 * j];
#pragma unroll
        for (int i = 0; i < 8; ++i) {
            m1out[(size_t)(m0 + tx + 16 * i) * H1_ + (n0 + ty + 16 * j)] =
                acc[i][j] + bj;
        }
    }
}

// ---------------------------------------------------------------------------
// Persistent per-sample SNN, membrane state in REGISTERS.
// Thread tid owns m1[tid+256k] k=0..7 and m2[tid+256k] k=0..3.
// LDS: spike bitmasks only (+ epilogue buffer).
// ---------------------------------------------------------------------------
__global__ __launch_bounds__(256) void k_snn(const double* __restrict__ m1_0,
                                             const float* __restrict__ b1,
                                             const float* __restrict__ W1T,  // [D_][H1_]
                                             const float* __restrict__ W2T,  // [H1_][H2_]
                                             const float* __restrict__ b2,
                                             const float* __restrict__ Wo,   // [C_][H2_]
                                             const float* __restrict__ bo,
                                             const int* __restrict__ nsteps_p,
                                             float* __restrict__ out) {
    __shared__ unsigned long long s1bits[H1_ / 64];  // 32 words
    __shared__ unsigned long long s2bits[H2_ / 64];  // 16 words
    __shared__ double pj[H2_];                       // epilogue: spike-rate (8 KB)

    int b = blockIdx.x;
    int tid = threadIdx.x;
    int lane = tid & 63;
    int wv = tid >> 6;      // wave id 0..3
    int T = nsteps_p[0];

    double m1r[8], m2r[4];
    float b1f[8], b2f[4];
    int cnt[4];

    const double* m1p = m1_0 + (size_t)b * H1_;
#pragma unroll
    for (int k = 0; k < 8; ++k) {
        m1r[k] = m1p[tid + 256 * k];
        b1f[k] = b1[tid + 256 * k];
    }
#pragma unroll
    for (int k = 0; k < 4; ++k) {
        m2r[k] = 0.0;
        b2f[k] = b2[tid + 256 * k];
        cnt[k] = 0;
    }

    for (int t = 0; t < T; ++t) {
        if (t > 0) {
            // ---- layer 1: m1 = 0.9*m1_old - r1(m1_old) + b1 + W1 @ s2_prev ----
#pragma unroll
            for (int k = 0; k < 8; ++k)
                m1r[k] = 0.9 * m1r[k] - (m1r[k] > 1.0 ? 1.0 : 0.0) + (double)b1f[k];
            for (int w = 0; w < H2_ / 64; ++w) {
                unsigned long long bits = s2bits[w];
                while (bits) {
                    int i2 = w * 64 + __builtin_ctzll(bits);
                    bits &= bits - 1;
                    const float* col = &W1T[(size_t)i2 * H1_];
#pragma unroll
                    for (int k = 0; k < 8; ++k)
                        m1r[k] += (double)col[tid + 256 * k];
                }
            }
        }
        // ---- s1 ballot: i = wv*64 + lane + 256k  ->  word wv + 4k, bit lane ----
#pragma unroll
        for (int k = 0; k < 8; ++k) {
            unsigned long long bal = __ballot(m1r[k] > 1.0);
            if (lane == 0) s1bits[wv + 4 * k] = bal;
        }
        // ---- layer 2 decay + bias (uses OLD m2) ----
#pragma unroll
        for (int k = 0; k < 4; ++k)
            m2r[k] = 0.9 * m2r[k] - (m2r[k] > 1.0 ? 1.0 : 0.0) + (double)b2f[k];
        __syncthreads();   // s1bits visible
        // ---- gather active s1 columns of W2T into m2 registers ----
        for (int w = 0; w < H1_ / 64; ++w) {
            unsigned long long bits = s1bits[w];
            while (bits) {
                int i1 = w * 64 + __builtin_ctzll(bits);
                bits &= bits - 1;
                const float* col = &W2T[(size_t)i1 * H2_];
#pragma unroll
                for (int k = 0; k < 4; ++k)
                    m2r[k] += (double)col[tid + 256 * k];
            }
        }
        // ---- s2 ballot + spike counts ----
#pragma unroll
        for (int k = 0; k < 4; ++k) {
            bool sp = m2r[k] > 1.0;
            cnt[k] += sp ? 1 : 0;
            unsigned long long bal = __ballot(sp);
            if (lane == 0) s2bits[wv + 4 * k] = bal;
        }
        __syncthreads();   // s2bits visible for next step's layer-1 gather
    }

    // ---- output: out[b][c] = bo[c] + sum_j (cnt[j]/T) * Wo[c][j] ----
#pragma unroll
    for (int k = 0; k < 4; ++k)
        pj[tid + 256 * k] = (double)cnt[k] / (double)T;
    __syncthreads();

    int c = tid >> 2, r = tid & 3;
    const float* worow = &Wo[(size_t)c * H2_];
    double acc = 0.0;
    for (int j = r; j < H2_; j += 4)
        acc += pj[j] * (double)worow[j];
    acc += __shfl_xor(acc, 1);
    acc += __shfl_xor(acc, 2);
    if (r == 0)
        out[(size_t)b * C_ + c] = (float)(acc + (double)bo[c]);
}

// ---------------------------------------------------------------------------
extern "C" void kernel_launch(void* const* d_in, const int* in_sizes, int n_in,
                              void* d_out, int out_size, void* d_ws, size_t ws_size,
                              hipStream_t stream) {
    const float* x  = (const float*)d_in[0];   // [4096,1024]
    const float* W1 = (const float*)d_in[1];   // [2048,1024]
    const float* b1 = (const float*)d_in[2];   // [2048]
    const float* W2 = (const float*)d_in[3];   // [1024,2048]
    const float* b2 = (const float*)d_in[4];   // [1024]
    const float* Wo = (const float*)d_in[5];   // [64,1024]
    const float* bo = (const float*)d_in[6];   // [64]
    const int* nst  = (const int*)d_in[7];     // [1] = 20
    float* out = (float*)d_out;

    // workspace layout
    size_t off_m1  = 0;                                   // f64 [4096][2048] = 64 MiB
    size_t off_w1t = off_m1 + (size_t)B_ * H1_ * 8;       // f32 [1024][2048] = 8 MiB
    size_t off_w2t = off_w1t + (size_t)D_ * H1_ * 4;      // f32 [2048][1024] = 8 MiB
    size_t need    = off_w2t + (size_t)H1_ * H2_ * 4;
    if (ws_size < need) return;

    double* m1ws = (double*)((char*)d_ws + off_m1);
    float*  W1T  = (float*)((char*)d_ws + off_w1t);
    float*  W2T  = (float*)((char*)d_ws + off_w2t);

    k_transpose<<<dim3(D_ / 32, H1_ / 32), dim3(32, 8), 0, stream>>>(W1, W1T, H1_, D_);
    k_transpose<<<dim3(H1_ / 32, H2_ / 32), dim3(32, 8), 0, stream>>>(W2, W2T, H2_, H1_);

    k_gemm1<<<dim3(B_ / BM, H1_ / BN), 256, 0, stream>>>(x, W1, b1, m1ws);

    k_snn<<<B_, 256, 0, stream>>>(m1ws, b1, W1T, W2T, b2, Wo, bo, nst, out);
}

// Round 3
// 973.918 us; speedup vs baseline: 1.5361x; 1.0007x over previous
//
#include <hip/hip_runtime.h>
#include <hip/hip_bf16.h>

// Sizes (fixed by the reference): B=4096, D=1024, H1=2048, H2=1024, C=64, T=20
#define B_   4096
#define D_   1024
#define H1_  2048
#define H2_  1024
#define C_   64

typedef double d4 __attribute__((ext_vector_type(4)));

#if defined(__has_builtin)
#if __has_builtin(__builtin_amdgcn_mfma_f64_16x16x4f64)
#define HAVE_MFMA64 1
#endif
#endif

// ---------------------------------------------------------------------------
// Probe: verify assumed v_mfma_f64_16x16x4 fragment layout at runtime.
// Assumed: A[r][k]: lane = r + 16k ; B[k][c]: lane = c + 16k ;
//          D[r][c]: lane: c = lane&15, r = 4*(lane>>4) + reg.
// ---------------------------------------------------------------------------
__global__ void k_probe(int* flag) {
#if defined(HAVE_MFMA64)
    int lane = threadIdx.x;
    int lr = lane & 15, lk = lane >> 4;
    double a = (double)(5 * lr + 3 * lk + 1);    // A[r][k] = 5r+3k+1
    double bb = (double)(2 * lr + 11 * lk + 2);  // B[k][c] = 11k+2c+2
    d4 c = {0.0, 0.0, 0.0, 0.0};
    c = __builtin_amdgcn_mfma_f64_16x16x4f64(a, bb, c, 0, 0, 0);
    int ok = 1;
#pragma unroll
    for (int j = 0; j < 4; ++j) {
        int r = 4 * lk + j;
        double e = 0.0;
        for (int k = 0; k < 4; ++k)
            e += (double)(5 * r + 3 * k + 1) * (double)(11 * k + 2 * lr + 2);
        if (c[j] != e) ok = 0;
    }
    unsigned long long all = __ballot(ok != 0);
    if (lane == 0) flag[0] = (all == ~0ULL) ? 1 : 0;
#else
    if (threadIdx.x == 0) flag[0] = 0;
#endif
}

// ---------------------------------------------------------------------------
// Transpose: out[c][r] = in[r][c]   (f32, 32x32 LDS tiles)
// ---------------------------------------------------------------------------
__global__ __launch_bounds__(256) void k_transpose(const float* __restrict__ in,
                                                   float* __restrict__ out,
                                                   int R, int C) {
    __shared__ float t[32][33];
    int c0 = blockIdx.x * 32;
    int r0 = blockIdx.y * 32;
    int lx = threadIdx.x;
    int ly = threadIdx.y;
#pragma unroll
    for (int q = 0; q < 4; ++q) {
        int rr = ly + 8 * q;
        t[rr][lx] = in[(size_t)(r0 + rr) * C + (c0 + lx)];
    }
    __syncthreads();
#pragma unroll
    for (int q = 0; q < 4; ++q) {
        int cc = ly + 8 * q;
        out[(size_t)(c0 + cc) * R + (r0 + lx)] = t[lx][cc];
    }
}

// ---------------------------------------------------------------------------
// f64 MFMA GEMM: m1_0[b][n] = sum_k x[b][k]*W1[n][k] + b1[n]
// 128x128 tile, BK=16, 4 waves, each wave 64x64 via 4x4 mfma_f64_16x16x4 tiles.
// Runs only if probe validated the fragment layout (flag==1).
// ---------------------------------------------------------------------------
#define GBM 128
#define GBN 128
#define GBK 16
__global__ __launch_bounds__(256) void k_gemm_mfma(const float* __restrict__ x,
                                                   const float* __restrict__ W1,
                                                   const float* __restrict__ b1,
                                                   double* __restrict__ m1out,
                                                   const int* __restrict__ flag) {
#if defined(HAVE_MFMA64)
    if (flag[0] != 1) return;
    __shared__ double As[GBK][GBM + 2];
    __shared__ double Bs[GBK][GBN + 2];

    int tid = threadIdx.x;
    int m0 = blockIdx.x * GBM;
    int n0 = blockIdx.y * GBN;
    int w = tid >> 6, lane = tid & 63;
    int wr = w >> 1, wc = w & 1;      // wave quadrant: rows wr*64, cols wc*64
    int lr = lane & 15, lk = lane >> 4;
    int srow = tid >> 1;              // staging row 0..127
    int skq = (tid & 1) * 8;          // staging k offset 0 or 8

    d4 acc[4][4];
#pragma unroll
    for (int i = 0; i < 4; ++i)
#pragma unroll
        for (int j = 0; j < 4; ++j) acc[i][j] = (d4){0.0, 0.0, 0.0, 0.0};

    for (int k0 = 0; k0 < D_; k0 += GBK) {
        float4 a0 = *(const float4*)&x [(size_t)(m0 + srow) * D_ + k0 + skq];
        float4 a1 = *(const float4*)&x [(size_t)(m0 + srow) * D_ + k0 + skq + 4];
        float4 g0 = *(const float4*)&W1[(size_t)(n0 + srow) * D_ + k0 + skq];
        float4 g1 = *(const float4*)&W1[(size_t)(n0 + srow) * D_ + k0 + skq + 4];
        __syncthreads();
        As[skq + 0][srow] = (double)a0.x;
        As[skq + 1][srow] = (double)a0.y;
        As[skq + 2][srow] = (double)a0.z;
        As[skq + 3][srow] = (double)a0.w;
        As[skq + 4][srow] = (double)a1.x;
        As[skq + 5][srow] = (double)a1.y;
        As[skq + 6][srow] = (double)a1.z;
        As[skq + 7][srow] = (double)a1.w;
        Bs[skq + 0][srow] = (double)g0.x;
        Bs[skq + 1][srow] = (double)g0.y;
        Bs[skq + 2][srow] = (double)g0.z;
        Bs[skq + 3][srow] = (double)g0.w;
        Bs[skq + 4][srow] = (double)g1.x;
        Bs[skq + 5][srow] = (double)g1.y;
        Bs[skq + 6][srow] = (double)g1.z;
        Bs[skq + 7][srow] = (double)g1.w;
        __syncthreads();
#pragma unroll
        for (int kb = 0; kb < 4; ++kb) {
            double a[4], bb[4];
#pragma unroll
            for (int i = 0; i < 4; ++i) a[i]  = As[kb * 4 + lk][wr * 64 + 16 * i + lr];
#pragma unroll
            for (int j = 0; j < 4; ++j) bb[j] = Bs[kb * 4 + lk][wc * 64 + 16 * j + lr];
#pragma unroll
            for (int i = 0; i < 4; ++i)
#pragma unroll
                for (int j = 0; j < 4; ++j)
                    acc[i][j] = __builtin_amdgcn_mfma_f64_16x16x4f64(a[i], bb[j], acc[i][j], 0, 0, 0);
        }
    }
#pragma unroll
    for (int j = 0; j < 4; ++j) {
        int col = n0 + wc * 64 + 16 * j + lr;
        double bj = (double)b1[col];
#pragma unroll
        for (int i = 0; i < 4; ++i)
#pragma unroll
            for (int r = 0; r < 4; ++r) {
                int row = m0 + wr * 64 + 16 * i + 4 * lk + r;
                m1out[(size_t)row * H1_ + col] = acc[i][j][r] + bj;
            }
    }
#else
    (void)x; (void)W1; (void)b1; (void)m1out; (void)flag;
#endif
}

// ---------------------------------------------------------------------------
// Fallback VALU f64 GEMM (proven round-2 kernel). Runs iff flag != 1.
// ---------------------------------------------------------------------------
#define BM 128
#define BN 128
#define BK 8
__global__ __launch_bounds__(256) void k_gemm1(const float* __restrict__ x,
                                               const float* __restrict__ W1,
                                               const float* __restrict__ b1,
                                               double* __restrict__ m1out,
                                               const int* __restrict__ flag) {
    if (flag[0] == 1) return;
    __shared__ double As[BK][BM + 4];
    __shared__ double Bs[BK][BN + 4];

    int tid = threadIdx.x;
    int m0 = blockIdx.x * BM;
    int n0 = blockIdx.y * BN;
    int tx = tid & 15;
    int ty = tid >> 4;
    int lr = tid >> 1;
    int lk = (tid & 1) * 4;

    double acc[8][8] = {};

    for (int k0 = 0; k0 < D_; k0 += BK) {
        float4 av = *(const float4*)&x [(size_t)(m0 + lr) * D_ + k0 + lk];
        float4 bv = *(const float4*)&W1[(size_t)(n0 + lr) * D_ + k0 + lk];
        __syncthreads();
        As[lk + 0][lr] = (double)av.x;
        As[lk + 1][lr] = (double)av.y;
        As[lk + 2][lr] = (double)av.z;
        As[lk + 3][lr] = (double)av.w;
        Bs[lk + 0][lr] = (double)bv.x;
        Bs[lk + 1][lr] = (double)bv.y;
        Bs[lk + 2][lr] = (double)bv.z;
        Bs[lk + 3][lr] = (double)bv.w;
        __syncthreads();
#pragma unroll
        for (int kk = 0; kk < BK; ++kk) {
            double a[8], b[8];
#pragma unroll
            for (int i = 0; i < 8; ++i) a[i] = As[kk][tx + 16 * i];
#pragma unroll
            for (int j = 0; j < 8; ++j) b[j] = Bs[kk][ty + 16 * j];
#pragma unroll
            for (int i = 0; i < 8; ++i)
#pragma unroll
                for (int j = 0; j < 8; ++j)
                    acc[i][j] += a[i] * b[j];
        }
    }
#pragma unroll
    for (int j = 0; j < 8; ++j) {
        double bj = (double)b1[n0 + ty + 16 * j];
#pragma unroll
        for (int i = 0; i < 8; ++i) {
            m1out[(size_t)(m0 + tx + 16 * i) * H1_ + (n0 + ty + 16 * j)] =
                acc[i][j] + bj;
        }
    }
}

// ---------------------------------------------------------------------------
// Persistent per-sample SNN, membrane state in registers, CONSECUTIVE ownership:
// thread tid owns m1[8*tid+q] (q<8) and m2[4*tid+q] (q<4) -> float4 gathers.
// Spike masks built via LDS byte/nibble packing (identity bit mapping).
// ---------------------------------------------------------------------------
__global__ __launch_bounds__(256) void k_snn(const double* __restrict__ m1_0,
                                             const float* __restrict__ b1,
                                             const float* __restrict__ W1T,  // [D_ rows of H1_]... [k][H1_]
                                             const float* __restrict__ W2T,  // [H1_][H2_]
                                             const float* __restrict__ b2,
                                             const float* __restrict__ Wo,   // [C_][H2_]
                                             const float* __restrict__ bo,
                                             const int* __restrict__ nsteps_p,
                                             float* __restrict__ out) {
    __shared__ unsigned long long s1by[32];   // 256 bytes: flag byte per thread
    __shared__ unsigned long long s1w[H1_ / 64];   // 32 words
    __shared__ unsigned long long s2nb[32];   // 256 bytes: nibble per thread
    __shared__ unsigned long long s2w[H2_ / 64];   // 16 words
    __shared__ double pj[H2_];                // epilogue

    int b = blockIdx.x;
    int tid = threadIdx.x;
    int T = nsteps_p[0];

    double m1r[8], m2r[4];
    float b1f[8], b2f[4];
    int cnt[4];

    const double* m1p = m1_0 + (size_t)b * H1_ + 8 * tid;
    {
        double2 v0 = *(const double2*)(m1p + 0);
        double2 v1 = *(const double2*)(m1p + 2);
        double2 v2 = *(const double2*)(m1p + 4);
        double2 v3 = *(const double2*)(m1p + 6);
        m1r[0] = v0.x; m1r[1] = v0.y; m1r[2] = v1.x; m1r[3] = v1.y;
        m1r[4] = v2.x; m1r[5] = v2.y; m1r[6] = v3.x; m1r[7] = v3.y;
    }
    {
        float4 f0 = *(const float4*)(b1 + 8 * tid);
        float4 f1 = *(const float4*)(b1 + 8 * tid + 4);
        b1f[0] = f0.x; b1f[1] = f0.y; b1f[2] = f0.z; b1f[3] = f0.w;
        b1f[4] = f1.x; b1f[5] = f1.y; b1f[6] = f1.z; b1f[7] = f1.w;
        float4 f2 = *(const float4*)(b2 + 4 * tid);
        b2f[0] = f2.x; b2f[1] = f2.y; b2f[2] = f2.z; b2f[3] = f2.w;
    }
#pragma unroll
    for (int q = 0; q < 4; ++q) { m2r[q] = 0.0; cnt[q] = 0; }
    if (tid < 16) s2w[tid] = 0ULL;
    __syncthreads();

    for (int t = 0; t < T; ++t) {
        if (t > 0) {
            // ---- layer 1: m1 = 0.9*m1_old - r1(m1_old) + b1 + W1 @ s2_prev ----
#pragma unroll
            for (int q = 0; q < 8; ++q)
                m1r[q] = 0.9 * m1r[q] - (m1r[q] > 1.0 ? 1.0 : 0.0) + (double)b1f[q];
            for (int w = 0; w < H2_ / 64; ++w) {
                unsigned long long bits = s2w[w];
                while (bits) {
                    int i2 = w * 64 + __builtin_ctzll(bits);
                    bits &= bits - 1;
                    const float4* c4 = (const float4*)(W1T + (size_t)i2 * H1_);
                    float4 v0 = c4[2 * tid];
                    float4 v1 = c4[2 * tid + 1];
                    m1r[0] += (double)v0.x; m1r[1] += (double)v0.y;
                    m1r[2] += (double)v0.z; m1r[3] += (double)v0.w;
                    m1r[4] += (double)v1.x; m1r[5] += (double)v1.y;
                    m1r[6] += (double)v1.z; m1r[7] += (double)v1.w;
                }
            }
        }
        // ---- s1 flags -> byte tid of 2048-bit array ----
        {
            unsigned bflag = 0;
#pragma unroll
            for (int q = 0; q < 8; ++q) bflag |= (m1r[q] > 1.0 ? 1u : 0u) << q;
            ((unsigned char*)s1by)[tid] = (unsigned char)bflag;
        }
        // ---- layer 2 decay + bias (uses OLD m2) ----
#pragma unroll
        for (int q = 0; q < 4; ++q)
            m2r[q] = 0.9 * m2r[q] - (m2r[q] > 1.0 ? 1.0 : 0.0) + (double)b2f[q];
        __syncthreads();   // s1 bytes written
        if (tid < 32) s1w[tid] = s1by[tid];   // bytes 8t..8t+7 == word t (identity)
        __syncthreads();   // s1 words ready
        // ---- gather active s1 columns of W2T ----
        for (int w = 0; w < H1_ / 64; ++w) {
            unsigned long long bits = s1w[w];
            while (bits) {
                int i1 = w * 64 + __builtin_ctzll(bits);
                bits &= bits - 1;
                const float4* c4 = (const float4*)(W2T + (size_t)i1 * H2_);
                float4 v = c4[tid];
                m2r[0] += (double)v.x; m2r[1] += (double)v.y;
                m2r[2] += (double)v.z; m2r[3] += (double)v.w;
            }
        }
        // ---- s2 flags (nibble) + counts ----
        {
            unsigned nib = 0;
#pragma unroll
            for (int q = 0; q < 4; ++q) {
                bool sp = m2r[q] > 1.0;
                cnt[q] += sp ? 1 : 0;
                nib |= (sp ? 1u : 0u) << q;
            }
            ((unsigned char*)s2nb)[tid] = (unsigned char)nib;
        }
        __syncthreads();   // nibbles written
        if (tid < 16) {
            unsigned long long w0 = s2nb[2 * tid];
            unsigned long long w1 = s2nb[2 * tid + 1];
            // compact low nibble of each byte -> 32 bits
            w0 &= 0x0F0F0F0F0F0F0F0FULL;
            w0 = (w0 | (w0 >> 4)) & 0x00FF00FF00FF00FFULL;
            w0 = (w0 | (w0 >> 8)) & 0x0000FFFF0000FFFFULL;
            w0 = (w0 | (w0 >> 16)) & 0x00000000FFFFFFFFULL;
            w1 &= 0x0F0F0F0F0F0F0F0FULL;
            w1 = (w1 | (w1 >> 4)) & 0x00FF00FF00FF00FFULL;
            w1 = (w1 | (w1 >> 8)) & 0x0000FFFF0000FFFFULL;
            w1 = (w1 | (w1 >> 16)) & 0x00000000FFFFFFFFULL;
            s2w[tid] = w0 | (w1 << 32);
        }
        __syncthreads();   // s2 words ready for next step
    }

    // ---- output: out[b][c] = bo[c] + sum_j (cnt[j]/T) * Wo[c][j] ----
#pragma unroll
    for (int q = 0; q < 4; ++q)
        pj[4 * tid + q] = (double)cnt[q] / (double)T;
    __syncthreads();

    int c = tid >> 2, r = tid & 3;
    const float* worow = &Wo[(size_t)c * H2_];
    double acc = 0.0;
    for (int j = r; j < H2_; j += 4)
        acc += pj[j] * (double)worow[j];
    acc += __shfl_xor(acc, 1);
    acc += __shfl_xor(acc, 2);
    if (r == 0)
        out[(size_t)b * C_ + c] = (float)(acc + (double)bo[c]);
}

// ---------------------------------------------------------------------------
extern "C" void kernel_launch(void* const* d_in, const int* in_sizes, int n_in,
                              void* d_out, int out_size, void* d_ws, size_t ws_size,
                              hipStream_t stream) {
    const float* x  = (const float*)d_in[0];   // [4096,1024]
    const float* W1 = (const float*)d_in[1];   // [2048,1024]
    const float* b1 = (const float*)d_in[2];   // [2048]
    const float* W2 = (const float*)d_in[3];   // [1024,2048]
    const float* b2 = (const float*)d_in[4];   // [1024]
    const float* Wo = (const float*)d_in[5];   // [64,1024]
    const float* bo = (const float*)d_in[6];   // [64]
    const int* nst  = (const int*)d_in[7];     // [1] = 20
    float* out = (float*)d_out;

    // workspace layout
    size_t off_m1   = 0;                                   // f64 [4096][2048] = 64 MiB
    size_t off_w1t  = off_m1 + (size_t)B_ * H1_ * 8;       // f32 [1024][2048] = 8 MiB
    size_t off_w2t  = off_w1t + (size_t)D_ * H1_ * 4;      // f32 [2048][1024] = 8 MiB
    size_t off_flag = off_w2t + (size_t)H1_ * H2_ * 4;
    size_t need     = off_flag + 64;
    if (ws_size < need) return;

    double* m1ws = (double*)((char*)d_ws + off_m1);
    float*  W1T  = (float*)((char*)d_ws + off_w1t);
    float*  W2T  = (float*)((char*)d_ws + off_w2t);
    int*    flag = (int*)((char*)d_ws + off_flag);

    k_probe<<<1, 64, 0, stream>>>(flag);

    k_transpose<<<dim3(D_ / 32, H1_ / 32), dim3(32, 8), 0, stream>>>(W1, W1T, H1_, D_);
    k_transpose<<<dim3(H1_ / 32, H2_ / 32), dim3(32, 8), 0, stream>>>(W2, W2T, H2_, H1_);

    k_gemm_mfma<<<dim3(B_ / GBM, H1_ / GBN), 256, 0, stream>>>(x, W1, b1, m1ws, flag);
    k_gemm1<<<dim3(B_ / BM, H1_ / BN), 256, 0, stream>>>(x, W1, b1, m1ws, flag);

    k_snn<<<B_, 256, 0, stream>>>(m1ws, b1, W1T, W2T, b2, Wo, bo, nst, out);
}

// Round 4
// 778.366 us; speedup vs baseline: 1.9220x; 1.2512x over previous
//
#include <hip/hip_runtime.h>
#include <hip/hip_bf16.h>

// Sizes (fixed by the reference): B=4096, D=1024, H1=2048, H2=1024, C=64, T=20
#define B_   4096
#define D_   1024
#define H1_  2048
#define H2_  1024
#define C_   64

typedef double d4 __attribute__((ext_vector_type(4)));

#if defined(__has_builtin)
#  if __has_builtin(__builtin_amdgcn_mfma_f64_16x16x4f64)
#    define MFMA64(A, B, C) __builtin_amdgcn_mfma_f64_16x16x4f64((A), (B), (C), 0, 0, 0)
#    define HAVE_MFMA64 1
#  elif __has_builtin(__builtin_amdgcn_mfma_f64_16x16x4_f64)
#    define MFMA64(A, B, C) __builtin_amdgcn_mfma_f64_16x16x4_f64((A), (B), (C), 0, 0, 0)
#    define HAVE_MFMA64 1
#  endif
#endif

// ---------------------------------------------------------------------------
// Probe: discover v_mfma_f64_16x16x4 D-fragment layout at runtime.
// A convention: A[r][k] at lane r+16k. B: B[k][c] at lane c+16k.
// D candidates (lr=lane&15, lk=lane>>4, j=reg):
//   1: row=4*lk+j, col=lr     2: row=lr, col=4*lk+j
//   3: row=lk+4*j, col=lr     4: row=lr, col=lk+4*j
// flag = matching candidate, 0 = none/builtin missing.
// ---------------------------------------------------------------------------
__global__ void k_probe(int* flag) {
#if defined(HAVE_MFMA64)
    int lane = threadIdx.x & 63;
    int lr = lane & 15, lk = lane >> 4;
    double a  = (double)(5 * lr + 3 * lk + 1);    // A[r][k] = 5r+3k+1
    double bb = (double)(11 * lk + 2 * lr + 2);   // B[k][c] = 11k+2c+2
    d4 c = {0.0, 0.0, 0.0, 0.0};
    c = MFMA64(a, bb, c);
    int okm[4] = {1, 1, 1, 1};
#pragma unroll
    for (int j = 0; j < 4; ++j) {
        double e1 = 0, e2 = 0, e3 = 0, e4 = 0;
        for (int k = 0; k < 4; ++k) {
            e1 += (double)(5 * (4 * lk + j) + 3 * k + 1) * (double)(11 * k + 2 * lr + 2);
            e2 += (double)(5 * lr + 3 * k + 1) * (double)(11 * k + 2 * (4 * lk + j) + 2);
            e3 += (double)(5 * (lk + 4 * j) + 3 * k + 1) * (double)(11 * k + 2 * lr + 2);
            e4 += (double)(5 * lr + 3 * k + 1) * (double)(11 * k + 2 * (lk + 4 * j) + 2);
        }
        if (c[j] != e1) okm[0] = 0;
        if (c[j] != e2) okm[1] = 0;
        if (c[j] != e3) okm[2] = 0;
        if (c[j] != e4) okm[3] = 0;
    }
    int f = 0;
    for (int m = 3; m >= 0; --m) {
        unsigned long long all = __ballot(okm[m] != 0);
        if (all == ~0ULL) f = m + 1;
    }
    if (lane == 0) flag[0] = f;
#else
    if ((threadIdx.x & 63) == 0) flag[0] = 0;
#endif
}

// ---------------------------------------------------------------------------
// Transpose: out[c][r] = in[r][c]   (f32, 32x32 LDS tiles)
// ---------------------------------------------------------------------------
__global__ __launch_bounds__(256) void k_transpose(const float* __restrict__ in,
                                                   float* __restrict__ out,
                                                   int R, int C) {
    __shared__ float t[32][33];
    int c0 = blockIdx.x * 32;
    int r0 = blockIdx.y * 32;
    int lx = threadIdx.x;
    int ly = threadIdx.y;
#pragma unroll
    for (int q = 0; q < 4; ++q) {
        int rr = ly + 8 * q;
        t[rr][lx] = in[(size_t)(r0 + rr) * C + (c0 + lx)];
    }
    __syncthreads();
#pragma unroll
    for (int q = 0; q < 4; ++q) {
        int cc = ly + 8 * q;
        out[(size_t)(c0 + cc) * R + (r0 + lx)] = t[lx][cc];
    }
}

// ---------------------------------------------------------------------------
// f64 MFMA GEMM: m1_0[b][n] = sum_k x[b][k]*W1[n][k] + b1[n]
// 128x128 tile, BK=16, 4 waves, each wave 64x64 via 4x4 mfma_f64_16x16x4 tiles.
// Runs iff flag in {1..4}; epilogue D-mapping selected by flag.
// ---------------------------------------------------------------------------
#define GBM 128
#define GBN 128
#define GBK 16
__global__ __launch_bounds__(256) void k_gemm_mfma(const float* __restrict__ x,
                                                   const float* __restrict__ W1,
                                                   const float* __restrict__ b1,
                                                   double* __restrict__ m1out,
                                                   const int* __restrict__ flag) {
#if defined(HAVE_MFMA64)
    int fm = flag[0];
    if (fm < 1 || fm > 4) return;
    __shared__ double As[GBK][GBM + 2];
    __shared__ double Bs[GBK][GBN + 2];

    int tid = threadIdx.x;
    int m0 = blockIdx.x * GBM;
    int n0 = blockIdx.y * GBN;
    int w = tid >> 6, lane = tid & 63;
    int wr = w >> 1, wc = w & 1;
    int lr = lane & 15, lk = lane >> 4;
    int srow = tid >> 1;
    int skq = (tid & 1) * 8;

    d4 acc[4][4];
#pragma unroll
    for (int i = 0; i < 4; ++i)
#pragma unroll
        for (int j = 0; j < 4; ++j) acc[i][j] = (d4){0.0, 0.0, 0.0, 0.0};

    for (int k0 = 0; k0 < D_; k0 += GBK) {
        float4 a0 = *(const float4*)&x [(size_t)(m0 + srow) * D_ + k0 + skq];
        float4 a1 = *(const float4*)&x [(size_t)(m0 + srow) * D_ + k0 + skq + 4];
        float4 g0 = *(const float4*)&W1[(size_t)(n0 + srow) * D_ + k0 + skq];
        float4 g1 = *(const float4*)&W1[(size_t)(n0 + srow) * D_ + k0 + skq + 4];
        __syncthreads();
        As[skq + 0][srow] = (double)a0.x;
        As[skq + 1][srow] = (double)a0.y;
        As[skq + 2][srow] = (double)a0.z;
        As[skq + 3][srow] = (double)a0.w;
        As[skq + 4][srow] = (double)a1.x;
        As[skq + 5][srow] = (double)a1.y;
        As[skq + 6][srow] = (double)a1.z;
        As[skq + 7][srow] = (double)a1.w;
        Bs[skq + 0][srow] = (double)g0.x;
        Bs[skq + 1][srow] = (double)g0.y;
        Bs[skq + 2][srow] = (double)g0.z;
        Bs[skq + 3][srow] = (double)g0.w;
        Bs[skq + 4][srow] = (double)g1.x;
        Bs[skq + 5][srow] = (double)g1.y;
        Bs[skq + 6][srow] = (double)g1.z;
        Bs[skq + 7][srow] = (double)g1.w;
        __syncthreads();
#pragma unroll
        for (int kb = 0; kb < 4; ++kb) {
            double a[4], bb[4];
#pragma unroll
            for (int i = 0; i < 4; ++i) a[i]  = As[kb * 4 + lk][wr * 64 + 16 * i + lr];
#pragma unroll
            for (int j = 0; j < 4; ++j) bb[j] = Bs[kb * 4 + lk][wc * 64 + 16 * j + lr];
#pragma unroll
            for (int i = 0; i < 4; ++i)
#pragma unroll
                for (int j = 0; j < 4; ++j)
                    acc[i][j] = MFMA64(a[i], bb[j], acc[i][j]);
        }
    }
    // epilogue: D-mapping selected by fm
#pragma unroll
    for (int j = 0; j < 4; ++j)
#pragma unroll
        for (int i = 0; i < 4; ++i)
#pragma unroll
            for (int r = 0; r < 4; ++r) {
                int rin = (fm == 1) ? (4 * lk + r) : (fm == 2) ? lr
                        : (fm == 3) ? (lk + 4 * r) : lr;
                int cin = (fm == 1) ? lr : (fm == 2) ? (4 * lk + r)
                        : (fm == 3) ? lr : (lk + 4 * r);
                int row = m0 + wr * 64 + 16 * i + rin;
                int col = n0 + wc * 64 + 16 * j + cin;
                m1out[(size_t)row * H1_ + col] = acc[i][j][r] + (double)b1[col];
            }
#else
    (void)x; (void)W1; (void)b1; (void)m1out; (void)flag;
#endif
}

// ---------------------------------------------------------------------------
// Fallback VALU f64 GEMM (proven). Runs iff flag not in {1..4}.
// ---------------------------------------------------------------------------
#define BM 128
#define BN 128
#define BK 8
__global__ __launch_bounds__(256) void k_gemm1(const float* __restrict__ x,
                                               const float* __restrict__ W1,
                                               const float* __restrict__ b1,
                                               double* __restrict__ m1out,
                                               const int* __restrict__ flag) {
    int fm = flag[0];
    if (fm >= 1 && fm <= 4) return;
    __shared__ double As[BK][BM + 4];
    __shared__ double Bs[BK][BN + 4];

    int tid = threadIdx.x;
    int m0 = blockIdx.x * BM;
    int n0 = blockIdx.y * BN;
    int tx = tid & 15;
    int ty = tid >> 4;
    int lr = tid >> 1;
    int lk = (tid & 1) * 4;

    double acc[8][8] = {};

    for (int k0 = 0; k0 < D_; k0 += BK) {
        float4 av = *(const float4*)&x [(size_t)(m0 + lr) * D_ + k0 + lk];
        float4 bv = *(const float4*)&W1[(size_t)(n0 + lr) * D_ + k0 + lk];
        __syncthreads();
        As[lk + 0][lr] = (double)av.x;
        As[lk + 1][lr] = (double)av.y;
        As[lk + 2][lr] = (double)av.z;
        As[lk + 3][lr] = (double)av.w;
        Bs[lk + 0][lr] = (double)bv.x;
        Bs[lk + 1][lr] = (double)bv.y;
        Bs[lk + 2][lr] = (double)bv.z;
        Bs[lk + 3][lr] = (double)bv.w;
        __syncthreads();
#pragma unroll
        for (int kk = 0; kk < BK; ++kk) {
            double a[8], b[8];
#pragma unroll
            for (int i = 0; i < 8; ++i) a[i] = As[kk][tx + 16 * i];
#pragma unroll
            for (int j = 0; j < 8; ++j) b[j] = Bs[kk][ty + 16 * j];
#pragma unroll
            for (int i = 0; i < 8; ++i)
#pragma unroll
                for (int j = 0; j < 8; ++j)
                    acc[i][j] += a[i] * b[j];
        }
    }
#pragma unroll
    for (int j = 0; j < 8; ++j) {
        double bj = (double)b1[n0 + ty + 16 * j];
#pragma unroll
        for (int i = 0; i < 8; ++i) {
            m1out[(size_t)(m0 + tx + 16 * i) * H1_ + (n0 + ty + 16 * j)] =
                acc[i][j] + bj;
        }
    }
}

// ---------------------------------------------------------------------------
// Persistent per-sample SNN. Registers hold state (consecutive ownership:
// m1[8*tid+q], m2[4*tid+q]). Spike masks -> wave-parallel index-list
// expansion -> 4-deep pipelined float4 column gathers.
// ---------------------------------------------------------------------------
__global__ __launch_bounds__(256) void k_snn(const double* __restrict__ m1_0,
                                             const float* __restrict__ b1,
                                             const float* __restrict__ W1T,  // [D? no: [H2 cols? ] [k][H1_]
                                             const float* __restrict__ W2T,  // [H1_][H2_]
                                             const float* __restrict__ b2,
                                             const float* __restrict__ Wo,   // [C_][H2_]
                                             const float* __restrict__ bo,
                                             const int* __restrict__ nsteps_p,
                                             float* __restrict__ out) {
    __shared__ unsigned long long s1by[32];   // 256 B: byte tid = s1 flags of m1[8t..8t+7]
    __shared__ unsigned long long s2nb[32];   // 256 B: byte tid = s2 nibble of m2[4t..4t+3]
    __shared__ short l1idx[H1_];              // 4 KB: active s1 column list
    __shared__ short l2idx[H2_];              // 2 KB: active s2 column list
    __shared__ int ncnt[2];
    __shared__ double pj[H2_];                // 8 KB: epilogue

    int b = blockIdx.x;
    int tid = threadIdx.x;
    int T = nsteps_p[0];

    double m1r[8], m2r[4];
    float b1f[8], b2f[4];
    int cnt[4];

    const double* m1p = m1_0 + (size_t)b * H1_ + 8 * tid;
    {
        double2 v0 = *(const double2*)(m1p + 0);
        double2 v1 = *(const double2*)(m1p + 2);
        double2 v2 = *(const double2*)(m1p + 4);
        double2 v3 = *(const double2*)(m1p + 6);
        m1r[0] = v0.x; m1r[1] = v0.y; m1r[2] = v1.x; m1r[3] = v1.y;
        m1r[4] = v2.x; m1r[5] = v2.y; m1r[6] = v3.x; m1r[7] = v3.y;
    }
    {
        float4 f0 = *(const float4*)(b1 + 8 * tid);
        float4 f1 = *(const float4*)(b1 + 8 * tid + 4);
        b1f[0] = f0.x; b1f[1] = f0.y; b1f[2] = f0.z; b1f[3] = f0.w;
        b1f[4] = f1.x; b1f[5] = f1.y; b1f[6] = f1.z; b1f[7] = f1.w;
        float4 f2 = *(const float4*)(b2 + 4 * tid);
        b2f[0] = f2.x; b2f[1] = f2.y; b2f[2] = f2.z; b2f[3] = f2.w;
    }
#pragma unroll
    for (int q = 0; q < 4; ++q) { m2r[q] = 0.0; cnt[q] = 0; }
    __syncthreads();

#define LOADC2(v, idx) v = ((const float4*)(W2T + ((size_t)(int)(idx) << 10)))[tid]
#define ACC2(v) { m2r[0] += (double)(v).x; m2r[1] += (double)(v).y; \
                  m2r[2] += (double)(v).z; m2r[3] += (double)(v).w; }

    for (int t = 0; t < T; ++t) {
        if (t > 0) {
            // ---- layer 1: m1 = 0.9*m1_old - r1(m1_old) + b1 + W1 @ s2_prev ----
#pragma unroll
            for (int q = 0; q < 8; ++q)
                m1r[q] = 0.9 * m1r[q] - (m1r[q] > 1.0 ? 1.0 : 0.0) + (double)b1f[q];
            int n2 = ncnt[1];
            for (int k2 = 0; k2 < n2; ++k2) {
                int i2 = l2idx[k2];
                const float4* c4 = (const float4*)(W1T + ((size_t)i2 << 11));
                float4 va = c4[2 * tid];
                float4 vb = c4[2 * tid + 1];
                m1r[0] += (double)va.x; m1r[1] += (double)va.y;
                m1r[2] += (double)va.z; m1r[3] += (double)va.w;
                m1r[4] += (double)vb.x; m1r[5] += (double)vb.y;
                m1r[6] += (double)vb.z; m1r[7] += (double)vb.w;
            }
        }
        // ---- s1 flags -> byte tid ----
        {
            unsigned bflag = 0;
#pragma unroll
            for (int q = 0; q < 8; ++q) bflag |= (m1r[q] > 1.0 ? 1u : 0u) << q;
            ((unsigned char*)s1by)[tid] = (unsigned char)bflag;
        }
        // ---- layer 2 decay + bias (uses OLD m2) ----
#pragma unroll
        for (int q = 0; q < 4; ++q)
            m2r[q] = 0.9 * m2r[q] - (m2r[q] > 1.0 ? 1.0 : 0.0) + (double)b2f[q];
        __syncthreads();   // s1 bytes visible
        // ---- wave 0: expand s1 mask -> l1idx (ascending) ----
        if (tid < 64) {
            unsigned long long bits = (tid < 32) ? s1by[tid] : 0ULL;
            int pc = __popcll(bits);
            int sc = pc;
#pragma unroll
            for (int d = 1; d < 64; d <<= 1) {
                int o = __shfl_up(sc, d);
                if (tid >= d) sc += o;
            }
            if (tid == 63) ncnt[0] = sc;
            int off = sc - pc;
            int base = tid << 6;
            while (bits) {
                l1idx[off++] = (short)(base + __builtin_ctzll(bits));
                bits &= bits - 1;
            }
        }
        __syncthreads();   // l1idx ready
        // ---- layer-2 gather: 4-deep pipelined float4 ----
        {
            int n1 = ncnt[0];
            float4 f0, f1, f2, f3;
            if (0 < n1) LOADC2(f0, l1idx[0]);
            if (1 < n1) LOADC2(f1, l1idx[1]);
            if (2 < n1) LOADC2(f2, l1idx[2]);
            if (3 < n1) LOADC2(f3, l1idx[3]);
            int proc = 0;
            while (proc + 4 <= n1) {
                float4 a0 = f0, a1 = f1, a2 = f2, a3 = f3;
                int p4 = proc + 4;
                if (p4 + 0 < n1) LOADC2(f0, l1idx[p4 + 0]);
                if (p4 + 1 < n1) LOADC2(f1, l1idx[p4 + 1]);
                if (p4 + 2 < n1) LOADC2(f2, l1idx[p4 + 2]);
                if (p4 + 3 < n1) LOADC2(f3, l1idx[p4 + 3]);
                ACC2(a0); ACC2(a1); ACC2(a2); ACC2(a3);
                proc = p4;
            }
            if (proc + 0 < n1) ACC2(f0);
            if (proc + 1 < n1) ACC2(f1);
            if (proc + 2 < n1) ACC2(f2);
            if (proc + 3 < n1) ACC2(f3);
        }
        // ---- s2 flags (nibble) + counts ----
        {
            unsigned nib = 0;
#pragma unroll
            for (int q = 0; q < 4; ++q) {
                bool sp = m2r[q] > 1.0;
                cnt[q] += sp ? 1 : 0;
                nib |= (sp ? 1u : 0u) << q;
            }
            ((unsigned char*)s2nb)[tid] = (unsigned char)nib;
        }
        __syncthreads();   // nibbles visible
        // ---- wave 0: compact nibbles -> words, expand -> l2idx ----
        if (tid < 64) {
            unsigned long long wbits = 0ULL;
            if (tid < 16) {
                unsigned long long w0 = s2nb[2 * tid];
                unsigned long long w1 = s2nb[2 * tid + 1];
                w0 &= 0x0F0F0F0F0F0F0F0FULL;
                w0 = (w0 | (w0 >> 4)) & 0x00FF00FF00FF00FFULL;
                w0 = (w0 | (w0 >> 8)) & 0x0000FFFF0000FFFFULL;
                w0 = (w0 | (w0 >> 16)) & 0x00000000FFFFFFFFULL;
                w1 &= 0x0F0F0F0F0F0F0F0FULL;
                w1 = (w1 | (w1 >> 4)) & 0x00FF00FF00FF00FFULL;
                w1 = (w1 | (w1 >> 8)) & 0x0000FFFF0000FFFFULL;
                w1 = (w1 | (w1 >> 16)) & 0x00000000FFFFFFFFULL;
                wbits = w0 | (w1 << 32);
            }
            int pc = __popcll(wbits);
            int sc = pc;
#pragma unroll
            for (int d = 1; d < 64; d <<= 1) {
                int o = __shfl_up(sc, d);
                if (tid >= d) sc += o;
            }
            if (tid == 63) ncnt[1] = sc;
            int off = sc - pc;
            int base = tid << 6;
            while (wbits) {
                l2idx[off++] = (short)(base + __builtin_ctzll(wbits));
                wbits &= wbits - 1;
            }
        }
        __syncthreads();   // l2idx ready for next step
    }
#undef LOADC2
#undef ACC2

    // ---- output: out[b][c] = bo[c] + sum_j (cnt[j]/T) * Wo[c][j] ----
#pragma unroll
    for (int q = 0; q < 4; ++q)
        pj[4 * tid + q] = (double)cnt[q] / (double)T;
    __syncthreads();

    int c = tid >> 2, r = tid & 3;
    const float* worow = &Wo[(size_t)c * H2_];
    double acc = 0.0;
    for (int j = r; j < H2_; j += 4)
        acc += pj[j] * (double)worow[j];
    acc += __shfl_xor(acc, 1);
    acc += __shfl_xor(acc, 2);
    if (r == 0)
        out[(size_t)b * C_ + c] = (float)(acc + (double)bo[c]);
}

// ---------------------------------------------------------------------------
extern "C" void kernel_launch(void* const* d_in, const int* in_sizes, int n_in,
                              void* d_out, int out_size, void* d_ws, size_t ws_size,
                              hipStream_t stream) {
    const float* x  = (const float*)d_in[0];   // [4096,1024]
    const float* W1 = (const float*)d_in[1];   // [2048,1024]
    const float* b1 = (const float*)d_in[2];   // [2048]
    const float* W2 = (const float*)d_in[3];   // [1024,2048]
    const float* b2 = (const float*)d_in[4];   // [1024]
    const float* Wo = (const float*)d_in[5];   // [64,1024]
    const float* bo = (const float*)d_in[6];   // [64]
    const int* nst  = (const int*)d_in[7];     // [1] = 20
    float* out = (float*)d_out;

    size_t off_m1   = 0;                                   // f64 [4096][2048]
    size_t off_w1t  = off_m1 + (size_t)B_ * H1_ * 8;
    size_t off_w2t  = off_w1t + (size_t)D_ * H1_ * 4;
    size_t off_flag = off_w2t + (size_t)H1_ * H2_ * 4;
    size_t need     = off_flag + 64;
    if (ws_size < need) return;

    double* m1ws = (double*)((char*)d_ws + off_m1);
    float*  W1T  = (float*)((char*)d_ws + off_w1t);
    float*  W2T  = (float*)((char*)d_ws + off_w2t);
    int*    flag = (int*)((char*)d_ws + off_flag);

    k_probe<<<1, 64, 0, stream>>>(flag);

    k_transpose<<<dim3(D_ / 32, H1_ / 32), dim3(32, 8), 0, stream>>>(W1, W1T, H1_, D_);
    k_transpose<<<dim3(H1_ / 32, H2_ / 32), dim3(32, 8), 0, stream>>>(W2, W2T, H2_, H1_);

    k_gemm_mfma<<<dim3(B_ / GBM, H1_ / GBN), 256, 0, stream>>>(x, W1, b1, m1ws, flag);
    k_gemm1<<<dim3(B_ / BM, H1_ / BN), 256, 0, stream>>>(x, W1, b1, m1ws, flag);

    k_snn<<<B_, 256, 0, stream>>>(m1ws, b1, W1T, W2T, b2, Wo, bo, nst, out);
}

// Round 5
// 658.090 us; speedup vs baseline: 2.2733x; 1.1828x over previous
//
#include <hip/hip_runtime.h>
#include <hip/hip_bf16.h>

// Sizes (fixed by the reference): B=4096, D=1024, H1=2048, H2=1024, C=64, T=20
#define B_   4096
#define D_   1024
#define H1_  2048
#define H2_  1024
#define C_   64

typedef double d4 __attribute__((ext_vector_type(4)));

#if defined(__has_builtin)
#  if __has_builtin(__builtin_amdgcn_mfma_f64_16x16x4f64)
#    define MFMA64(A, B, C) __builtin_amdgcn_mfma_f64_16x16x4f64((A), (B), (C), 0, 0, 0)
#    define HAVE_MFMA64 1
#  elif __has_builtin(__builtin_amdgcn_mfma_f64_16x16x4_f64)
#    define MFMA64(A, B, C) __builtin_amdgcn_mfma_f64_16x16x4_f64((A), (B), (C), 0, 0, 0)
#    define HAVE_MFMA64 1
#  endif
#endif

// ---------------------------------------------------------------------------
// Probe: discover v_mfma_f64_16x16x4 D-fragment layout at runtime.
// A convention: A[r][k] at lane r+16k. B: B[k][c] at lane c+16k.
// D candidates (lr=lane&15, lk=lane>>4, j=reg):
//   1: row=4*lk+j, col=lr     2: row=lr, col=4*lk+j
//   3: row=lk+4*j, col=lr     4: row=lr, col=lk+4*j
// ---------------------------------------------------------------------------
__global__ void k_probe(int* flag) {
#if defined(HAVE_MFMA64)
    int lane = threadIdx.x & 63;
    int lr = lane & 15, lk = lane >> 4;
    double a  = (double)(5 * lr + 3 * lk + 1);    // A[r][k] = 5r+3k+1
    double bb = (double)(11 * lk + 2 * lr + 2);   // B[k][c] = 11k+2c+2
    d4 c = {0.0, 0.0, 0.0, 0.0};
    c = MFMA64(a, bb, c);
    int okm[4] = {1, 1, 1, 1};
#pragma unroll
    for (int j = 0; j < 4; ++j) {
        double e1 = 0, e2 = 0, e3 = 0, e4 = 0;
        for (int k = 0; k < 4; ++k) {
            e1 += (double)(5 * (4 * lk + j) + 3 * k + 1) * (double)(11 * k + 2 * lr + 2);
            e2 += (double)(5 * lr + 3 * k + 1) * (double)(11 * k + 2 * (4 * lk + j) + 2);
            e3 += (double)(5 * (lk + 4 * j) + 3 * k + 1) * (double)(11 * k + 2 * lr + 2);
            e4 += (double)(5 * lr + 3 * k + 1) * (double)(11 * k + 2 * (lk + 4 * j) + 2);
        }
        if (c[j] != e1) okm[0] = 0;
        if (c[j] != e2) okm[1] = 0;
        if (c[j] != e3) okm[2] = 0;
        if (c[j] != e4) okm[3] = 0;
    }
    int f = 0;
    for (int m = 3; m >= 0; --m) {
        unsigned long long all = __ballot(okm[m] != 0);
        if (all == ~0ULL) f = m + 1;
    }
    if (lane == 0) flag[0] = f;
#else
    if ((threadIdx.x & 63) == 0) flag[0] = 0;
#endif
}

// ---------------------------------------------------------------------------
// Transpose: out[c][r] = in[r][c]   (f32, 32x32 LDS tiles)
// ---------------------------------------------------------------------------
__global__ __launch_bounds__(256) void k_transpose(const float* __restrict__ in,
                                                   float* __restrict__ out,
                                                   int R, int C) {
    __shared__ float t[32][33];
    int c0 = blockIdx.x * 32;
    int r0 = blockIdx.y * 32;
    int lx = threadIdx.x;
    int ly = threadIdx.y;
#pragma unroll
    for (int q = 0; q < 4; ++q) {
        int rr = ly + 8 * q;
        t[rr][lx] = in[(size_t)(r0 + rr) * C + (c0 + lx)];
    }
    __syncthreads();
#pragma unroll
    for (int q = 0; q < 4; ++q) {
        int cc = ly + 8 * q;
        out[(size_t)(c0 + cc) * R + (r0 + lx)] = t[lx][cc];
    }
}

// ---------------------------------------------------------------------------
// f64 MFMA GEMM v2: 128x128 tile, 512 threads (8 waves), wave-tile 64x32.
// LDS holds f32 (converted to f64 at fragment read — exact).
// Pad leading dim to 136: lk-groups 8 banks apart -> max 2-way (free).
// __launch_bounds__(512,4): VGPR<=128 -> 2 blocks/CU = 4 waves/SIMD.
// ---------------------------------------------------------------------------
#define GBM 128
#define GBN 128
#define GBK 16
#define LDP 136
__global__ __launch_bounds__(512, 4) void k_gemm_mfma(const float* __restrict__ x,
                                                      const float* __restrict__ W1,
                                                      const float* __restrict__ b1,
                                                      double* __restrict__ m1out,
                                                      const int* __restrict__ flag) {
#if defined(HAVE_MFMA64)
    int fm = flag[0];
    if (fm < 1 || fm > 4) return;
    __shared__ float As[GBK][LDP];   // 8704 B
    __shared__ float Bs[GBK][LDP];   // 8704 B

    int tid = threadIdx.x;
    int m0 = blockIdx.x * GBM;
    int n0 = blockIdx.y * GBN;
    int w = tid >> 6, lane = tid & 63;
    int wr = w >> 2;        // 0..1 : 64-row half
    int wc = w & 3;         // 0..3 : 32-col quarter
    int lr = lane & 15, lk = lane >> 4;
    int srow = tid >> 2;           // 0..127
    int skq = (tid & 3) * 4;       // 0,4,8,12

    d4 acc[4][2];
#pragma unroll
    for (int i = 0; i < 4; ++i)
#pragma unroll
        for (int j = 0; j < 2; ++j) acc[i][j] = (d4){0.0, 0.0, 0.0, 0.0};

    for (int k0 = 0; k0 < D_; k0 += GBK) {
        float4 av = *(const float4*)&x [(size_t)(m0 + srow) * D_ + k0 + skq];
        float4 bv = *(const float4*)&W1[(size_t)(n0 + srow) * D_ + k0 + skq];
        __syncthreads();
        As[skq + 0][srow] = av.x;
        As[skq + 1][srow] = av.y;
        As[skq + 2][srow] = av.z;
        As[skq + 3][srow] = av.w;
        Bs[skq + 0][srow] = bv.x;
        Bs[skq + 1][srow] = bv.y;
        Bs[skq + 2][srow] = bv.z;
        Bs[skq + 3][srow] = bv.w;
        __syncthreads();
#pragma unroll
        for (int kb = 0; kb < 4; ++kb) {
            double a[4], bfr[2];
#pragma unroll
            for (int i = 0; i < 4; ++i)
                a[i] = (double)As[kb * 4 + lk][wr * 64 + 16 * i + lr];
#pragma unroll
            for (int j = 0; j < 2; ++j)
                bfr[j] = (double)Bs[kb * 4 + lk][wc * 32 + 16 * j + lr];
#pragma unroll
            for (int i = 0; i < 4; ++i)
#pragma unroll
                for (int j = 0; j < 2; ++j)
                    acc[i][j] = MFMA64(a[i], bfr[j], acc[i][j]);
        }
    }
    // epilogue: D-mapping selected by fm
#pragma unroll
    for (int j = 0; j < 2; ++j)
#pragma unroll
        for (int i = 0; i < 4; ++i)
#pragma unroll
            for (int r = 0; r < 4; ++r) {
                int rin = (fm == 1) ? (4 * lk + r) : (fm == 2) ? lr
                        : (fm == 3) ? (lk + 4 * r) : lr;
                int cin = (fm == 1) ? lr : (fm == 2) ? (4 * lk + r)
                        : (fm == 3) ? lr : (lk + 4 * r);
                int row = m0 + wr * 64 + 16 * i + rin;
                int col = n0 + wc * 32 + 16 * j + cin;
                m1out[(size_t)row * H1_ + col] = acc[i][j][r] + (double)b1[col];
            }
#else
    (void)x; (void)W1; (void)b1; (void)m1out; (void)flag;
#endif
}

// ---------------------------------------------------------------------------
// Fallback VALU f64 GEMM (proven). Runs iff flag not in {1..4}.
// ---------------------------------------------------------------------------
#define BM 128
#define BN 128
#define BK 8
__global__ __launch_bounds__(256) void k_gemm1(const float* __restrict__ x,
                                               const float* __restrict__ W1,
                                               const float* __restrict__ b1,
                                               double* __restrict__ m1out,
                                               const int* __restrict__ flag) {
    int fm = flag[0];
    if (fm >= 1 && fm <= 4) return;
    __shared__ double As[BK][BM + 4];
    __shared__ double Bs[BK][BN + 4];

    int tid = threadIdx.x;
    int m0 = blockIdx.x * BM;
    int n0 = blockIdx.y * BN;
    int tx = tid & 15;
    int ty = tid >> 4;
    int lr = tid >> 1;
    int lk = (tid & 1) * 4;

    double acc[8][8] = {};

    for (int k0 = 0; k0 < D_; k0 += BK) {
        float4 av = *(const float4*)&x [(size_t)(m0 + lr) * D_ + k0 + lk];
        float4 bv = *(const float4*)&W1[(size_t)(n0 + lr) * D_ + k0 + lk];
        __syncthreads();
        As[lk + 0][lr] = (double)av.x;
        As[lk + 1][lr] = (double)av.y;
        As[lk + 2][lr] = (double)av.z;
        As[lk + 3][lr] = (double)av.w;
        Bs[lk + 0][lr] = (double)bv.x;
        Bs[lk + 1][lr] = (double)bv.y;
        Bs[lk + 2][lr] = (double)bv.z;
        Bs[lk + 3][lr] = (double)bv.w;
        __syncthreads();
#pragma unroll
        for (int kk = 0; kk < BK; ++kk) {
            double a[8], b[8];
#pragma unroll
            for (int i = 0; i < 8; ++i) a[i] = As[kk][tx + 16 * i];
#pragma unroll
            for (int j = 0; j < 8; ++j) b[j] = Bs[kk][ty + 16 * j];
#pragma unroll
            for (int i = 0; i < 8; ++i)
#pragma unroll
                for (int j = 0; j < 8; ++j)
                    acc[i][j] += a[i] * b[j];
        }
    }
#pragma unroll
    for (int j = 0; j < 8; ++j) {
        double bj = (double)b1[n0 + ty + 16 * j];
#pragma unroll
        for (int i = 0; i < 8; ++i) {
            m1out[(size_t)(m0 + tx + 16 * i) * H1_ + (n0 + ty + 16 * j)] =
                acc[i][j] + bj;
        }
    }
}

// ---------------------------------------------------------------------------
// Persistent per-sample SNN. Registers hold state (consecutive ownership:
// m1[8*tid+q], m2[4*tid+q]). Spike masks -> wave-parallel index-list
// expansion -> 4-deep pipelined float4 column gathers.
// ---------------------------------------------------------------------------
__global__ __launch_bounds__(256) void k_snn(const double* __restrict__ m1_0,
                                             const float* __restrict__ b1,
                                             const float* __restrict__ W1T,  // [H2 idx][H1_] col stride 2048
                                             const float* __restrict__ W2T,  // [H1_][H2_]
                                             const float* __restrict__ b2,
                                             const float* __restrict__ Wo,   // [C_][H2_]
                                             const float* __restrict__ bo,
                                             const int* __restrict__ nsteps_p,
                                             float* __restrict__ out) {
    __shared__ unsigned long long s1by[32];   // 256 B: byte tid = s1 flags of m1[8t..8t+7]
    __shared__ unsigned long long s2nb[32];   // 256 B: byte tid = s2 nibble of m2[4t..4t+3]
    __shared__ short l1idx[H1_];              // 4 KB: active s1 column list
    __shared__ short l2idx[H2_];              // 2 KB: active s2 column list
    __shared__ int ncnt[2];
    __shared__ double pj[H2_];                // 8 KB: epilogue

    int b = blockIdx.x;
    int tid = threadIdx.x;
    int T = nsteps_p[0];

    double m1r[8], m2r[4];
    float b1f[8], b2f[4];
    int cnt[4];

    const double* m1p = m1_0 + (size_t)b * H1_ + 8 * tid;
    {
        double2 v0 = *(const double2*)(m1p + 0);
        double2 v1 = *(const double2*)(m1p + 2);
        double2 v2 = *(const double2*)(m1p + 4);
        double2 v3 = *(const double2*)(m1p + 6);
        m1r[0] = v0.x; m1r[1] = v0.y; m1r[2] = v1.x; m1r[3] = v1.y;
        m1r[4] = v2.x; m1r[5] = v2.y; m1r[6] = v3.x; m1r[7] = v3.y;
    }
    {
        float4 f0 = *(const float4*)(b1 + 8 * tid);
        float4 f1 = *(const float4*)(b1 + 8 * tid + 4);
        b1f[0] = f0.x; b1f[1] = f0.y; b1f[2] = f0.z; b1f[3] = f0.w;
        b1f[4] = f1.x; b1f[5] = f1.y; b1f[6] = f1.z; b1f[7] = f1.w;
        float4 f2 = *(const float4*)(b2 + 4 * tid);
        b2f[0] = f2.x; b2f[1] = f2.y; b2f[2] = f2.z; b2f[3] = f2.w;
    }
#pragma unroll
    for (int q = 0; q < 4; ++q) { m2r[q] = 0.0; cnt[q] = 0; }
    __syncthreads();

#define LOADC2(v, idx) v = ((const float4*)(W2T + ((size_t)(int)(idx) << 10)))[tid]
#define ACC2(v) { m2r[0] += (double)(v).x; m2r[1] += (double)(v).y; \
                  m2r[2] += (double)(v).z; m2r[3] += (double)(v).w; }

    for (int t = 0; t < T; ++t) {
        if (t > 0) {
            // ---- layer 1: m1 = 0.9*m1_old - r1(m1_old) + b1 + W1 @ s2_prev ----
#pragma unroll
            for (int q = 0; q < 8; ++q)
                m1r[q] = 0.9 * m1r[q] - (m1r[q] > 1.0 ? 1.0 : 0.0) + (double)b1f[q];
            int n2 = ncnt[1];
            for (int k2 = 0; k2 < n2; ++k2) {
                int i2 = l2idx[k2];
                const float4* c4 = (const float4*)(W1T + ((size_t)i2 << 11));
                float4 va = c4[2 * tid];
                float4 vb = c4[2 * tid + 1];
                m1r[0] += (double)va.x; m1r[1] += (double)va.y;
                m1r[2] += (double)va.z; m1r[3] += (double)va.w;
                m1r[4] += (double)vb.x; m1r[5] += (double)vb.y;
                m1r[6] += (double)vb.z; m1r[7] += (double)vb.w;
            }
        }
        // ---- s1 flags -> byte tid ----
        {
            unsigned bflag = 0;
#pragma unroll
            for (int q = 0; q < 8; ++q) bflag |= (m1r[q] > 1.0 ? 1u : 0u) << q;
            ((unsigned char*)s1by)[tid] = (unsigned char)bflag;
        }
        // ---- layer 2 decay + bias (uses OLD m2) ----
#pragma unroll
        for (int q = 0; q < 4; ++q)
            m2r[q] = 0.9 * m2r[q] - (m2r[q] > 1.0 ? 1.0 : 0.0) + (double)b2f[q];
        __syncthreads();   // s1 bytes visible
        // ---- wave 0: expand s1 mask -> l1idx (ascending) ----
        if (tid < 64) {
            unsigned long long bits = (tid < 32) ? s1by[tid] : 0ULL;
            int pc = __popcll(bits);
            int sc = pc;
#pragma unroll
            for (int d = 1; d < 64; d <<= 1) {
                int o = __shfl_up(sc, d);
                if (tid >= d) sc += o;
            }
            if (tid == 63) ncnt[0] = sc;
            int off = sc - pc;
            int base = tid << 6;
            while (bits) {
                l1idx[off++] = (short)(base + __builtin_ctzll(bits));
                bits &= bits - 1;
            }
        }
        __syncthreads();   // l1idx ready
        // ---- layer-2 gather: 4-deep pipelined float4 ----
        {
            int n1 = ncnt[0];
            float4 f0, f1, f2, f3;
            if (0 < n1) LOADC2(f0, l1idx[0]);
            if (1 < n1) LOADC2(f1, l1idx[1]);
            if (2 < n1) LOADC2(f2, l1idx[2]);
            if (3 < n1) LOADC2(f3, l1idx[3]);
            int proc = 0;
            while (proc + 4 <= n1) {
                float4 a0 = f0, a1 = f1, a2 = f2, a3 = f3;
                int p4 = proc + 4;
                if (p4 + 0 < n1) LOADC2(f0, l1idx[p4 + 0]);
                if (p4 + 1 < n1) LOADC2(f1, l1idx[p4 + 1]);
                if (p4 + 2 < n1) LOADC2(f2, l1idx[p4 + 2]);
                if (p4 + 3 < n1) LOADC2(f3, l1idx[p4 + 3]);
                ACC2(a0); ACC2(a1); ACC2(a2); ACC2(a3);
                proc = p4;
            }
            if (proc + 0 < n1) ACC2(f0);
            if (proc + 1 < n1) ACC2(f1);
            if (proc + 2 < n1) ACC2(f2);
            if (proc + 3 < n1) ACC2(f3);
        }
        // ---- s2 flags (nibble) + counts ----
        {
            unsigned nib = 0;
#pragma unroll
            for (int q = 0; q < 4; ++q) {
                bool sp = m2r[q] > 1.0;
                cnt[q] += sp ? 1 : 0;
                nib |= (sp ? 1u : 0u) << q;
            }
            ((unsigned char*)s2nb)[tid] = (unsigned char)nib;
        }
        __syncthreads();   // nibbles visible
        // ---- wave 0: compact nibbles -> words, expand -> l2idx ----
        if (tid < 64) {
            unsigned long long wbits = 0ULL;
            if (tid < 16) {
                unsigned long long w0 = s2nb[2 * tid];
                unsigned long long w1 = s2nb[2 * tid + 1];
                w0 &= 0x0F0F0F0F0F0F0F0FULL;
                w0 = (w0 | (w0 >> 4)) & 0x00FF00FF00FF00FFULL;
                w0 = (w0 | (w0 >> 8)) & 0x0000FFFF0000FFFFULL;
                w0 = (w0 | (w0 >> 16)) & 0x00000000FFFFFFFFULL;
                w1 &= 0x0F0F0F0F0F0F0F0FULL;
                w1 = (w1 | (w1 >> 4)) & 0x00FF00FF00FF00FFULL;
                w1 = (w1 | (w1 >> 8)) & 0x0000FFFF0000FFFFULL;
                w1 = (w1 | (w1 >> 16)) & 0x00000000FFFFFFFFULL;
                wbits = w0 | (w1 << 32);
            }
            int pc = __popcll(wbits);
            int sc = pc;
#pragma unroll
            for (int d = 1; d < 64; d <<= 1) {
                int o = __shfl_up(sc, d);
                if (tid >= d) sc += o;
            }
            if (tid == 63) ncnt[1] = sc;
            int off = sc - pc;
            int base = tid << 6;
            while (wbits) {
                l2idx[off++] = (short)(base + __builtin_ctzll(wbits));
                wbits &= wbits - 1;
            }
        }
        __syncthreads();   // l2idx ready for next step
    }
#undef LOADC2
#undef ACC2

    // ---- output: out[b][c] = bo[c] + sum_j (cnt[j]/T) * Wo[c][j] ----
#pragma unroll
    for (int q = 0; q < 4; ++q)
        pj[4 * tid + q] = (double)cnt[q] / (double)T;
    __syncthreads();

    int c = tid >> 2, r = tid & 3;
    const float* worow = &Wo[(size_t)c * H2_];
    double acc = 0.0;
    for (int j = r; j < H2_; j += 4)
        acc += pj[j] * (double)worow[j];
    acc += __shfl_xor(acc, 1);
    acc += __shfl_xor(acc, 2);
    if (r == 0)
        out[(size_t)b * C_ + c] = (float)(acc + (double)bo[c]);
}

// ---------------------------------------------------------------------------
extern "C" void kernel_launch(void* const* d_in, const int* in_sizes, int n_in,
                              void* d_out, int out_size, void* d_ws, size_t ws_size,
                              hipStream_t stream) {
    const float* x  = (const float*)d_in[0];   // [4096,1024]
    const float* W1 = (const float*)d_in[1];   // [2048,1024]
    const float* b1 = (const float*)d_in[2];   // [2048]
    const float* W2 = (const float*)d_in[3];   // [1024,2048]
    const float* b2 = (const float*)d_in[4];   // [1024]
    const float* Wo = (const float*)d_in[5];   // [64,1024]
    const float* bo = (const float*)d_in[6];   // [64]
    const int* nst  = (const int*)d_in[7];     // [1] = 20
    float* out = (float*)d_out;

    size_t off_m1   = 0;                                   // f64 [4096][2048]
    size_t off_w1t  = off_m1 + (size_t)B_ * H1_ * 8;
    size_t off_w2t  = off_w1t + (size_t)D_ * H1_ * 4;
    size_t off_flag = off_w2t + (size_t)H1_ * H2_ * 4;
    size_t need     = off_flag + 64;
    if (ws_size < need) return;

    double* m1ws = (double*)((char*)d_ws + off_m1);
    float*  W1T  = (float*)((char*)d_ws + off_w1t);
    float*  W2T  = (float*)((char*)d_ws + off_w2t);
    int*    flag = (int*)((char*)d_ws + off_flag);

    k_probe<<<1, 64, 0, stream>>>(flag);

    k_transpose<<<dim3(D_ / 32, H1_ / 32), dim3(32, 8), 0, stream>>>(W1, W1T, H1_, D_);
    k_transpose<<<dim3(H1_ / 32, H2_ / 32), dim3(32, 8), 0, stream>>>(W2, W2T, H2_, H1_);

    k_gemm_mfma<<<dim3(B_ / GBM, H1_ / GBN), 512, 0, stream>>>(x, W1, b1, m1ws, flag);
    k_gemm1<<<dim3(B_ / BM, H1_ / BN), 256, 0, stream>>>(x, W1, b1, m1ws, flag);

    k_snn<<<B_, 256, 0, stream>>>(m1ws, b1, W1T, W2T, b2, Wo, bo, nst, out);
}

// Round 6
// 583.545 us; speedup vs baseline: 2.5637x; 1.1277x over previous
//
#include <hip/hip_runtime.h>
#include <hip/hip_bf16.h>

// Sizes (fixed by the reference): B=4096, D=1024, H1=2048, H2=1024, C=64, T=20
#define B_   4096
#define D_   1024
#define H1_  2048
#define H2_  1024
#define C_   64

typedef double d4 __attribute__((ext_vector_type(4)));

#if defined(__has_builtin)
#  if __has_builtin(__builtin_amdgcn_mfma_f64_16x16x4f64)
#    define MFMA64(A, B, C) __builtin_amdgcn_mfma_f64_16x16x4f64((A), (B), (C), 0, 0, 0)
#    define HAVE_MFMA64 1
#  elif __has_builtin(__builtin_amdgcn_mfma_f64_16x16x4_f64)
#    define MFMA64(A, B, C) __builtin_amdgcn_mfma_f64_16x16x4_f64((A), (B), (C), 0, 0, 0)
#    define HAVE_MFMA64 1
#  endif
#endif

// ---------------------------------------------------------------------------
// Probe: discover v_mfma_f64_16x16x4 D-fragment layout at runtime.
// ---------------------------------------------------------------------------
__global__ void k_probe(int* flag) {
#if defined(HAVE_MFMA64)
    int lane = threadIdx.x & 63;
    int lr = lane & 15, lk = lane >> 4;
    double a  = (double)(5 * lr + 3 * lk + 1);    // A[r][k] = 5r+3k+1
    double bb = (double)(11 * lk + 2 * lr + 2);   // B[k][c] = 11k+2c+2
    d4 c = {0.0, 0.0, 0.0, 0.0};
    c = MFMA64(a, bb, c);
    int okm[4] = {1, 1, 1, 1};
#pragma unroll
    for (int j = 0; j < 4; ++j) {
        double e1 = 0, e2 = 0, e3 = 0, e4 = 0;
        for (int k = 0; k < 4; ++k) {
            e1 += (double)(5 * (4 * lk + j) + 3 * k + 1) * (double)(11 * k + 2 * lr + 2);
            e2 += (double)(5 * lr + 3 * k + 1) * (double)(11 * k + 2 * (4 * lk + j) + 2);
            e3 += (double)(5 * (lk + 4 * j) + 3 * k + 1) * (double)(11 * k + 2 * lr + 2);
            e4 += (double)(5 * lr + 3 * k + 1) * (double)(11 * k + 2 * (lk + 4 * j) + 2);
        }
        if (c[j] != e1) okm[0] = 0;
        if (c[j] != e2) okm[1] = 0;
        if (c[j] != e3) okm[2] = 0;
        if (c[j] != e4) okm[3] = 0;
    }
    int f = 0;
    for (int m = 3; m >= 0; --m) {
        unsigned long long all = __ballot(okm[m] != 0);
        if (all == ~0ULL) f = m + 1;
    }
    if (lane == 0) flag[0] = f;
#else
    if ((threadIdx.x & 63) == 0) flag[0] = 0;
#endif
}

// ---------------------------------------------------------------------------
// Transpose: out[c][r] = in[r][c]   (f32, 32x32 LDS tiles)
// ---------------------------------------------------------------------------
__global__ __launch_bounds__(256) void k_transpose(const float* __restrict__ in,
                                                   float* __restrict__ out,
                                                   int R, int C) {
    __shared__ float t[32][33];
    int c0 = blockIdx.x * 32;
    int r0 = blockIdx.y * 32;
    int lx = threadIdx.x;
    int ly = threadIdx.y;
#pragma unroll
    for (int q = 0; q < 4; ++q) {
        int rr = ly + 8 * q;
        t[rr][lx] = in[(size_t)(r0 + rr) * C + (c0 + lx)];
    }
    __syncthreads();
#pragma unroll
    for (int q = 0; q < 4; ++q) {
        int cc = ly + 8 * q;
        out[(size_t)(c0 + cc) * R + (r0 + lx)] = t[lx][cc];
    }
}

// ---------------------------------------------------------------------------
// f64 MFMA GEMM v2 (unchanged from R5): 128x128, 512 thr, wave-tile 64x32,
// f32 LDS (exact convert at read), pad 136, launch_bounds(512,4).
// ---------------------------------------------------------------------------
#define GBM 128
#define GBN 128
#define GBK 16
#define LDP 136
__global__ __launch_bounds__(512, 4) void k_gemm_mfma(const float* __restrict__ x,
                                                      const float* __restrict__ W1,
                                                      const float* __restrict__ b1,
                                                      double* __restrict__ m1out,
                                                      const int* __restrict__ flag) {
#if defined(HAVE_MFMA64)
    int fm = flag[0];
    if (fm < 1 || fm > 4) return;
    __shared__ float As[GBK][LDP];
    __shared__ float Bs[GBK][LDP];

    int tid = threadIdx.x;
    int m0 = blockIdx.x * GBM;
    int n0 = blockIdx.y * GBN;
    int w = tid >> 6, lane = tid & 63;
    int wr = w >> 2;
    int wc = w & 3;
    int lr = lane & 15, lk = lane >> 4;
    int srow = tid >> 2;
    int skq = (tid & 3) * 4;

    d4 acc[4][2];
#pragma unroll
    for (int i = 0; i < 4; ++i)
#pragma unroll
        for (int j = 0; j < 2; ++j) acc[i][j] = (d4){0.0, 0.0, 0.0, 0.0};

    for (int k0 = 0; k0 < D_; k0 += GBK) {
        float4 av = *(const float4*)&x [(size_t)(m0 + srow) * D_ + k0 + skq];
        float4 bv = *(const float4*)&W1[(size_t)(n0 + srow) * D_ + k0 + skq];
        __syncthreads();
        As[skq + 0][srow] = av.x;
        As[skq + 1][srow] = av.y;
        As[skq + 2][srow] = av.z;
        As[skq + 3][srow] = av.w;
        Bs[skq + 0][srow] = bv.x;
        Bs[skq + 1][srow] = bv.y;
        Bs[skq + 2][srow] = bv.z;
        Bs[skq + 3][srow] = bv.w;
        __syncthreads();
#pragma unroll
        for (int kb = 0; kb < 4; ++kb) {
            double a[4], bfr[2];
#pragma unroll
            for (int i = 0; i < 4; ++i)
                a[i] = (double)As[kb * 4 + lk][wr * 64 + 16 * i + lr];
#pragma unroll
            for (int j = 0; j < 2; ++j)
                bfr[j] = (double)Bs[kb * 4 + lk][wc * 32 + 16 * j + lr];
#pragma unroll
            for (int i = 0; i < 4; ++i)
#pragma unroll
                for (int j = 0; j < 2; ++j)
                    acc[i][j] = MFMA64(a[i], bfr[j], acc[i][j]);
        }
    }
#pragma unroll
    for (int j = 0; j < 2; ++j)
#pragma unroll
        for (int i = 0; i < 4; ++i)
#pragma unroll
            for (int r = 0; r < 4; ++r) {
                int rin = (fm == 1) ? (4 * lk + r) : (fm == 2) ? lr
                        : (fm == 3) ? (lk + 4 * r) : lr;
                int cin = (fm == 1) ? lr : (fm == 2) ? (4 * lk + r)
                        : (fm == 3) ? lr : (lk + 4 * r);
                int row = m0 + wr * 64 + 16 * i + rin;
                int col = n0 + wc * 32 + 16 * j + cin;
                m1out[(size_t)row * H1_ + col] = acc[i][j][r] + (double)b1[col];
            }
#else
    (void)x; (void)W1; (void)b1; (void)m1out; (void)flag;
#endif
}

// ---------------------------------------------------------------------------
// Fallback VALU f64 GEMM (proven). Runs iff flag not in {1..4}.
// ---------------------------------------------------------------------------
#define BM 128
#define BN 128
#define BK 8
__global__ __launch_bounds__(256) void k_gemm1(const float* __restrict__ x,
                                               const float* __restrict__ W1,
                                               const float* __restrict__ b1,
                                               double* __restrict__ m1out,
                                               const int* __restrict__ flag) {
    int fm = flag[0];
    if (fm >= 1 && fm <= 4) return;
    __shared__ double As[BK][BM + 4];
    __shared__ double Bs[BK][BN + 4];

    int tid = threadIdx.x;
    int m0 = blockIdx.x * BM;
    int n0 = blockIdx.y * BN;
    int tx = tid & 15;
    int ty = tid >> 4;
    int lr = tid >> 1;
    int lk = (tid & 1) * 4;

    double acc[8][8] = {};

    for (int k0 = 0; k0 < D_; k0 += BK) {
        float4 av = *(const float4*)&x [(size_t)(m0 + lr) * D_ + k0 + lk];
        float4 bv = *(const float4*)&W1[(size_t)(n0 + lr) * D_ + k0 + lk];
        __syncthreads();
        As[lk + 0][lr] = (double)av.x;
        As[lk + 1][lr] = (double)av.y;
        As[lk + 2][lr] = (double)av.z;
        As[lk + 3][lr] = (double)av.w;
        Bs[lk + 0][lr] = (double)bv.x;
        Bs[lk + 1][lr] = (double)bv.y;
        Bs[lk + 2][lr] = (double)bv.z;
        Bs[lk + 3][lr] = (double)bv.w;
        __syncthreads();
#pragma unroll
        for (int kk = 0; kk < BK; ++kk) {
            double a[8], b[8];
#pragma unroll
            for (int i = 0; i < 8; ++i) a[i] = As[kk][tx + 16 * i];
#pragma unroll
            for (int j = 0; j < 8; ++j) b[j] = Bs[kk][ty + 16 * j];
#pragma unroll
            for (int i = 0; i < 8; ++i)
#pragma unroll
                for (int j = 0; j < 8; ++j)
                    acc[i][j] += a[i] * b[j];
        }
    }
#pragma unroll
    for (int j = 0; j < 8; ++j) {
        double bj = (double)b1[n0 + ty + 16 * j];
#pragma unroll
        for (int i = 0; i < 8; ++i) {
            m1out[(size_t)(m0 + tx + 16 * i) * H1_ + (n0 + ty + 16 * j)] =
                acc[i][j] + bj;
        }
    }
}

// ---------------------------------------------------------------------------
// Persistent per-sample SNN v3. Register state (m1[8t+q], m2[4t+q]).
// Gathers: int BYTE-OFFSET index lists, 8-deep register-batched float4 loads.
// Block-any fast path skips scan/sync machinery in spike-free steps.
// Arithmetic values & order identical to R5 (absmax 0 preserved).
// ---------------------------------------------------------------------------
__global__ __launch_bounds__(256) void k_snn(const double* __restrict__ m1_0,
                                             const float* __restrict__ b1,
                                             const float* __restrict__ W1T,  // [H2 idx][H1_] (8 KB cols)
                                             const float* __restrict__ W2T,  // [H1 idx][H2_] (4 KB cols)
                                             const float* __restrict__ b2,
                                             const float* __restrict__ Wo,   // [C_][H2_]
                                             const float* __restrict__ bo,
                                             const int* __restrict__ nsteps_p,
                                             float* __restrict__ out) {
    __shared__ __align__(16) double pjbuf[H2_];      // 8 KB: epilogue; aliased as l1idx
    __shared__ __align__(16) int l2idx[H2_];         // 4 KB
    __shared__ unsigned long long s1by[32];          // 256 B
    __shared__ unsigned long long s2nb[32];          // 256 B
    __shared__ int ncnt[2];
    __shared__ int anybuf[4];

    int* l1idx = (int*)pjbuf;                        // union with epilogue buffer

    int b = blockIdx.x;
    int tid = threadIdx.x;
    int lane = tid & 63;
    int wv = tid >> 6;
    int T = nsteps_p[0];

    double m1r[8], m2r[4];
    float b1f[8], b2f[4];
    int cnt[4];

    const double* m1p = m1_0 + (size_t)b * H1_ + 8 * tid;
    {
        double2 v0 = *(const double2*)(m1p + 0);
        double2 v1 = *(const double2*)(m1p + 2);
        double2 v2 = *(const double2*)(m1p + 4);
        double2 v3 = *(const double2*)(m1p + 6);
        m1r[0] = v0.x; m1r[1] = v0.y; m1r[2] = v1.x; m1r[3] = v1.y;
        m1r[4] = v2.x; m1r[5] = v2.y; m1r[6] = v3.x; m1r[7] = v3.y;
    }
    {
        float4 f0 = *(const float4*)(b1 + 8 * tid);
        float4 f1 = *(const float4*)(b1 + 8 * tid + 4);
        b1f[0] = f0.x; b1f[1] = f0.y; b1f[2] = f0.z; b1f[3] = f0.w;
        b1f[4] = f1.x; b1f[5] = f1.y; b1f[6] = f1.z; b1f[7] = f1.w;
        float4 f2 = *(const float4*)(b2 + 4 * tid);
        b2f[0] = f2.x; b2f[1] = f2.y; b2f[2] = f2.z; b2f[3] = f2.w;
    }
#pragma unroll
    for (int q = 0; q < 4; ++q) { m2r[q] = 0.0; cnt[q] = 0; }

    int anyS2 = 0;   // carried: any layer-2 spikes from previous step

#define ACC2(v) { m2r[0] += (double)(v).x; m2r[1] += (double)(v).y; \
                  m2r[2] += (double)(v).z; m2r[3] += (double)(v).w; }

    for (int t = 0; t < T; ++t) {
        if (t > 0) {
            // ---- layer 1: m1 = 0.9*m1_old - r1(m1_old) + b1 + W1 @ s2_prev ----
#pragma unroll
            for (int q = 0; q < 8; ++q)
                m1r[q] = 0.9 * m1r[q] - (m1r[q] > 1.0 ? 1.0 : 0.0) + (double)b1f[q];
            if (anyS2) {
                int n2 = ncnt[1];
                const char* Wc = (const char*)W1T;
                size_t toff = (size_t)tid << 5;            // tid*32 bytes (2 float4)
                for (int k2 = 0; k2 < n2; ++k2) {
                    const float4* c4 = (const float4*)(Wc + l2idx[k2] + toff);
                    float4 va = c4[0];
                    float4 vb = c4[1];
                    m1r[0] += (double)va.x; m1r[1] += (double)va.y;
                    m1r[2] += (double)va.z; m1r[3] += (double)va.w;
                    m1r[4] += (double)vb.x; m1r[5] += (double)vb.y;
                    m1r[6] += (double)vb.z; m1r[7] += (double)vb.w;
                }
            }
        }
        // ---- s1 flags -> byte tid ----
        unsigned bflag = 0;
#pragma unroll
        for (int q = 0; q < 8; ++q) bflag |= (m1r[q] > 1.0 ? 1u : 0u) << q;
        ((unsigned char*)s1by)[tid] = (unsigned char)bflag;
        // ---- layer 2 decay + bias (uses OLD m2) ----
#pragma unroll
        for (int q = 0; q < 4; ++q)
            m2r[q] = 0.9 * m2r[q] - (m2r[q] > 1.0 ? 1.0 : 0.0) + (double)b2f[q];
        // ---- block-any(s1) ; sync makes s1by visible ----
        {
            int wa = __any((int)bflag);
            if (lane == 0) anybuf[wv] = wa;
        }
        __syncthreads();
        int any1 = anybuf[0] | anybuf[1] | anybuf[2] | anybuf[3];
        if (any1) {
            // ---- wave 0: expand s1 mask -> l1idx (ascending byte offsets) ----
            if (tid < 64) {
                unsigned long long bits = (tid < 32) ? s1by[tid] : 0ULL;
                int pc = __popcll(bits);
                int sc = pc;
#pragma unroll
                for (int d = 1; d < 64; d <<= 1) {
                    int o = __shfl_up(sc, d);
                    if (tid >= d) sc += o;
                }
                if (tid == 63) ncnt[0] = sc;
                int off = sc - pc;
                int base = tid << 6;
                while (bits) {
                    l1idx[off++] = (base + __builtin_ctzll(bits)) << 12;  // *4096 B
                    bits &= bits - 1;
                }
            }
            __syncthreads();   // l1idx, ncnt[0] ready
            // ---- layer-2 gather: 8-deep register-batched float4 ----
            {
                int n1 = ncnt[0];
                const char* Wc = (const char*)W2T;
                size_t toff = (size_t)tid << 4;            // tid*16 bytes
                int k = 0;
                for (; k + 8 <= n1; k += 8) {
                    int4 oa = *(const int4*)&l1idx[k];
                    int4 ob = *(const int4*)&l1idx[k + 4];
                    float4 v0 = *(const float4*)(Wc + oa.x + toff);
                    float4 v1 = *(const float4*)(Wc + oa.y + toff);
                    float4 v2 = *(const float4*)(Wc + oa.z + toff);
                    float4 v3 = *(const float4*)(Wc + oa.w + toff);
                    float4 v4 = *(const float4*)(Wc + ob.x + toff);
                    float4 v5 = *(const float4*)(Wc + ob.y + toff);
                    float4 v6 = *(const float4*)(Wc + ob.z + toff);
                    float4 v7 = *(const float4*)(Wc + ob.w + toff);
                    ACC2(v0); ACC2(v1); ACC2(v2); ACC2(v3);
                    ACC2(v4); ACC2(v5); ACC2(v6); ACC2(v7);
                }
                for (; k < n1; ++k) {
                    float4 v = *(const float4*)(Wc + l1idx[k] + toff);
                    ACC2(v);
                }
            }
        }
        // ---- s2 flags (nibble) + counts ----
        unsigned nib = 0;
#pragma unroll
        for (int q = 0; q < 4; ++q) {
            bool sp = m2r[q] > 1.0;
            cnt[q] += sp ? 1 : 0;
            nib |= (sp ? 1u : 0u) << q;
        }
        ((unsigned char*)s2nb)[tid] = (unsigned char)nib;
        // ---- block-any(s2) ; sync makes nibbles visible ----
        {
            int wa = __any((int)nib);
            if (lane == 0) anybuf[wv] = wa;
        }
        __syncthreads();
        anyS2 = anybuf[0] | anybuf[1] | anybuf[2] | anybuf[3];
        if (anyS2) {
            // ---- wave 0: compact nibbles -> words, expand -> l2idx ----
            if (tid < 64) {
                unsigned long long wbits = 0ULL;
                if (tid < 16) {
                    unsigned long long w0 = s2nb[2 * tid];
                    unsigned long long w1 = s2nb[2 * tid + 1];
                    w0 &= 0x0F0F0F0F0F0F0F0FULL;
                    w0 = (w0 | (w0 >> 4)) & 0x00FF00FF00FF00FFULL;
                    w0 = (w0 | (w0 >> 8)) & 0x0000FFFF0000FFFFULL;
                    w0 = (w0 | (w0 >> 16)) & 0x00000000FFFFFFFFULL;
                    w1 &= 0x0F0F0F0F0F0F0F0FULL;
                    w1 = (w1 | (w1 >> 4)) & 0x00FF00FF00FF00FFULL;
                    w1 = (w1 | (w1 >> 8)) & 0x0000FFFF0000FFFFULL;
                    w1 = (w1 | (w1 >> 16)) & 0x00000000FFFFFFFFULL;
                    wbits = w0 | (w1 << 32);
                }
                int pc = __popcll(wbits);
                int sc = pc;
#pragma unroll
                for (int d = 1; d < 64; d <<= 1) {
                    int o = __shfl_up(sc, d);
                    if (tid >= d) sc += o;
                }
                if (tid == 63) ncnt[1] = sc;
                int off = sc - pc;
                int base = tid << 6;
                while (wbits) {
                    l2idx[off++] = (base + __builtin_ctzll(wbits)) << 13;  // *8192 B
                    wbits &= wbits - 1;
                }
            }
            __syncthreads();   // l2idx, ncnt[1] ready for next step
        }
    }
#undef ACC2

    // ---- output: out[b][c] = bo[c] + sum_j (cnt[j]/T) * Wo[c][j] ----
    __syncthreads();   // ensure all loop-phase reads of pjbuf alias are done
#pragma unroll
    for (int q = 0; q < 4; ++q)
        pjbuf[4 * tid + q] = (double)cnt[q] / (double)T;
    __syncthreads();

    int c = tid >> 2, r = tid & 3;
    const float* worow = &Wo[(size_t)c * H2_];
    double acc = 0.0;
    for (int j = r; j < H2_; j += 4)
        acc += pjbuf[j] * (double)worow[j];
    acc += __shfl_xor(acc, 1);
    acc += __shfl_xor(acc, 2);
    if (r == 0)
        out[(size_t)b * C_ + c] = (float)(acc + (double)bo[c]);
}

// ---------------------------------------------------------------------------
extern "C" void kernel_launch(void* const* d_in, const int* in_sizes, int n_in,
                              void* d_out, int out_size, void* d_ws, size_t ws_size,
                              hipStream_t stream) {
    const float* x  = (const float*)d_in[0];   // [4096,1024]
    const float* W1 = (const float*)d_in[1];   // [2048,1024]
    const float* b1 = (const float*)d_in[2];   // [2048]
    const float* W2 = (const float*)d_in[3];   // [1024,2048]
    const float* b2 = (const float*)d_in[4];   // [1024]
    const float* Wo = (const float*)d_in[5];   // [64,1024]
    const float* bo = (const float*)d_in[6];   // [64]
    const int* nst  = (const int*)d_in[7];     // [1] = 20
    float* out = (float*)d_out;

    size_t off_m1   = 0;                                   // f64 [4096][2048]
    size_t off_w1t  = off_m1 + (size_t)B_ * H1_ * 8;
    size_t off_w2t  = off_w1t + (size_t)D_ * H1_ * 4;
    size_t off_flag = off_w2t + (size_t)H1_ * H2_ * 4;
    size_t need     = off_flag + 64;
    if (ws_size < need) return;

    double* m1ws = (double*)((char*)d_ws + off_m1);
    float*  W1T  = (float*)((char*)d_ws + off_w1t);
    float*  W2T  = (float*)((char*)d_ws + off_w2t);
    int*    flag = (int*)((char*)d_ws + off_flag);

    k_probe<<<1, 64, 0, stream>>>(flag);

    k_transpose<<<dim3(D_ / 32, H1_ / 32), dim3(32, 8), 0, stream>>>(W1, W1T, H1_, D_);
    k_transpose<<<dim3(H1_ / 32, H2_ / 32), dim3(32, 8), 0, stream>>>(W2, W2T, H2_, H1_);

    k_gemm_mfma<<<dim3(B_ / GBM, H1_ / GBN), 512, 0, stream>>>(x, W1, b1, m1ws, flag);
    k_gemm1<<<dim3(B_ / BM, H1_ / BN), 256, 0, stream>>>(x, W1, b1, m1ws, flag);

    k_snn<<<B_, 256, 0, stream>>>(m1ws, b1, W1T, W2T, b2, Wo, bo, nst, out);
}

// Round 7
// 446.450 us; speedup vs baseline: 3.3510x; 1.3071x over previous
//
#include <hip/hip_runtime.h>
#include <hip/hip_bf16.h>

// Sizes (fixed by the reference): B=4096, D=1024, H1=2048, H2=1024, C=64, T=20
#define B_   4096
#define D_   1024
#define H1_  2048
#define H2_  1024
#define C_   64

typedef double d4 __attribute__((ext_vector_type(4)));

#if defined(__has_builtin)
#  if __has_builtin(__builtin_amdgcn_mfma_f64_16x16x4f64)
#    define MFMA64(A, B, C) __builtin_amdgcn_mfma_f64_16x16x4f64((A), (B), (C), 0, 0, 0)
#    define HAVE_MFMA64 1
#  elif __has_builtin(__builtin_amdgcn_mfma_f64_16x16x4_f64)
#    define MFMA64(A, B, C) __builtin_amdgcn_mfma_f64_16x16x4_f64((A), (B), (C), 0, 0, 0)
#    define HAVE_MFMA64 1
#  endif
#endif

// ---------------------------------------------------------------------------
// Probe: discover v_mfma_f64_16x16x4 D-fragment layout at runtime.
// ---------------------------------------------------------------------------
__global__ void k_probe(int* flag) {
#if defined(HAVE_MFMA64)
    int lane = threadIdx.x & 63;
    int lr = lane & 15, lk = lane >> 4;
    double a  = (double)(5 * lr + 3 * lk + 1);    // A[r][k] = 5r+3k+1
    double bb = (double)(11 * lk + 2 * lr + 2);   // B[k][c] = 11k+2c+2
    d4 c = {0.0, 0.0, 0.0, 0.0};
    c = MFMA64(a, bb, c);
    int okm[4] = {1, 1, 1, 1};
#pragma unroll
    for (int j = 0; j < 4; ++j) {
        double e1 = 0, e2 = 0, e3 = 0, e4 = 0;
        for (int k = 0; k < 4; ++k) {
            e1 += (double)(5 * (4 * lk + j) + 3 * k + 1) * (double)(11 * k + 2 * lr + 2);
            e2 += (double)(5 * lr + 3 * k + 1) * (double)(11 * k + 2 * (4 * lk + j) + 2);
            e3 += (double)(5 * (lk + 4 * j) + 3 * k + 1) * (double)(11 * k + 2 * lr + 2);
            e4 += (double)(5 * lr + 3 * k + 1) * (double)(11 * k + 2 * (lk + 4 * j) + 2);
        }
        if (c[j] != e1) okm[0] = 0;
        if (c[j] != e2) okm[1] = 0;
        if (c[j] != e3) okm[2] = 0;
        if (c[j] != e4) okm[3] = 0;
    }
    int f = 0;
    for (int m = 3; m >= 0; --m) {
        unsigned long long all = __ballot(okm[m] != 0);
        if (all == ~0ULL) f = m + 1;
    }
    if (lane == 0) flag[0] = f;
#else
    if ((threadIdx.x & 63) == 0) flag[0] = 0;
#endif
}

// ---------------------------------------------------------------------------
// Transpose: out[c][r] = in[r][c]   (f32, 32x32 LDS tiles)
// ---------------------------------------------------------------------------
__global__ __launch_bounds__(256) void k_transpose(const float* __restrict__ in,
                                                   float* __restrict__ out,
                                                   int R, int C) {
    __shared__ float t[32][33];
    int c0 = blockIdx.x * 32;
    int r0 = blockIdx.y * 32;
    int lx = threadIdx.x;
    int ly = threadIdx.y;
#pragma unroll
    for (int q = 0; q < 4; ++q) {
        int rr = ly + 8 * q;
        t[rr][lx] = in[(size_t)(r0 + rr) * C + (c0 + lx)];
    }
    __syncthreads();
#pragma unroll
    for (int q = 0; q < 4; ++q) {
        int cc = ly + 8 * q;
        out[(size_t)(c0 + cc) * R + (r0 + lx)] = t[lx][cc];
    }
}

// ---------------------------------------------------------------------------
// f64 MFMA GEMM v2 (unchanged, ~87% of f64 peak): 128x128, 512 thr,
// wave-tile 64x32, f32 LDS (exact convert at read), pad 136, lb(512,4).
// ---------------------------------------------------------------------------
#define GBM 128
#define GBN 128
#define GBK 16
#define LDP 136
__global__ __launch_bounds__(512, 4) void k_gemm_mfma(const float* __restrict__ x,
                                                      const float* __restrict__ W1,
                                                      const float* __restrict__ b1,
                                                      double* __restrict__ m1out,
                                                      const int* __restrict__ flag) {
#if defined(HAVE_MFMA64)
    int fm = flag[0];
    if (fm < 1 || fm > 4) return;
    __shared__ float As[GBK][LDP];
    __shared__ float Bs[GBK][LDP];

    int tid = threadIdx.x;
    int m0 = blockIdx.x * GBM;
    int n0 = blockIdx.y * GBN;
    int w = tid >> 6, lane = tid & 63;
    int wr = w >> 2;
    int wc = w & 3;
    int lr = lane & 15, lk = lane >> 4;
    int srow = tid >> 2;
    int skq = (tid & 3) * 4;

    d4 acc[4][2];
#pragma unroll
    for (int i = 0; i < 4; ++i)
#pragma unroll
        for (int j = 0; j < 2; ++j) acc[i][j] = (d4){0.0, 0.0, 0.0, 0.0};

    for (int k0 = 0; k0 < D_; k0 += GBK) {
        float4 av = *(const float4*)&x [(size_t)(m0 + srow) * D_ + k0 + skq];
        float4 bv = *(const float4*)&W1[(size_t)(n0 + srow) * D_ + k0 + skq];
        __syncthreads();
        As[skq + 0][srow] = av.x;
        As[skq + 1][srow] = av.y;
        As[skq + 2][srow] = av.z;
        As[skq + 3][srow] = av.w;
        Bs[skq + 0][srow] = bv.x;
        Bs[skq + 1][srow] = bv.y;
        Bs[skq + 2][srow] = bv.z;
        Bs[skq + 3][srow] = bv.w;
        __syncthreads();
#pragma unroll
        for (int kb = 0; kb < 4; ++kb) {
            double a[4], bfr[2];
#pragma unroll
            for (int i = 0; i < 4; ++i)
                a[i] = (double)As[kb * 4 + lk][wr * 64 + 16 * i + lr];
#pragma unroll
            for (int j = 0; j < 2; ++j)
                bfr[j] = (double)Bs[kb * 4 + lk][wc * 32 + 16 * j + lr];
#pragma unroll
            for (int i = 0; i < 4; ++i)
#pragma unroll
                for (int j = 0; j < 2; ++j)
                    acc[i][j] = MFMA64(a[i], bfr[j], acc[i][j]);
        }
    }
#pragma unroll
    for (int j = 0; j < 2; ++j)
#pragma unroll
        for (int i = 0; i < 4; ++i)
#pragma unroll
            for (int r = 0; r < 4; ++r) {
                int rin = (fm == 1) ? (4 * lk + r) : (fm == 2) ? lr
                        : (fm == 3) ? (lk + 4 * r) : lr;
                int cin = (fm == 1) ? lr : (fm == 2) ? (4 * lk + r)
                        : (fm == 3) ? lr : (lk + 4 * r);
                int row = m0 + wr * 64 + 16 * i + rin;
                int col = n0 + wc * 32 + 16 * j + cin;
                m1out[(size_t)row * H1_ + col] = acc[i][j][r] + (double)b1[col];
            }
#else
    (void)x; (void)W1; (void)b1; (void)m1out; (void)flag;
#endif
}

// ---------------------------------------------------------------------------
// Fallback VALU f64 GEMM (proven). Runs iff flag not in {1..4}.
// ---------------------------------------------------------------------------
#define BM 128
#define BN 128
#define BK 8
__global__ __launch_bounds__(256) void k_gemm1(const float* __restrict__ x,
                                               const float* __restrict__ W1,
                                               const float* __restrict__ b1,
                                               double* __restrict__ m1out,
                                               const int* __restrict__ flag) {
    int fm = flag[0];
    if (fm >= 1 && fm <= 4) return;
    __shared__ double As[BK][BM + 4];
    __shared__ double Bs[BK][BN + 4];

    int tid = threadIdx.x;
    int m0 = blockIdx.x * BM;
    int n0 = blockIdx.y * BN;
    int tx = tid & 15;
    int ty = tid >> 4;
    int lr = tid >> 1;
    int lk = (tid & 1) * 4;

    double acc[8][8] = {};

    for (int k0 = 0; k0 < D_; k0 += BK) {
        float4 av = *(const float4*)&x [(size_t)(m0 + lr) * D_ + k0 + lk];
        float4 bv = *(const float4*)&W1[(size_t)(n0 + lr) * D_ + k0 + lk];
        __syncthreads();
        As[lk + 0][lr] = (double)av.x;
        As[lk + 1][lr] = (double)av.y;
        As[lk + 2][lr] = (double)av.z;
        As[lk + 3][lr] = (double)av.w;
        Bs[lk + 0][lr] = (double)bv.x;
        Bs[lk + 1][lr] = (double)bv.y;
        Bs[lk + 2][lr] = (double)bv.z;
        Bs[lk + 3][lr] = (double)bv.w;
        __syncthreads();
#pragma unroll
        for (int kk = 0; kk < BK; ++kk) {
            double a[8], b[8];
#pragma unroll
            for (int i = 0; i < 8; ++i) a[i] = As[kk][tx + 16 * i];
#pragma unroll
            for (int j = 0; j < 8; ++j) b[j] = Bs[kk][ty + 16 * j];
#pragma unroll
            for (int i = 0; i < 8; ++i)
#pragma unroll
                for (int j = 0; j < 8; ++j)
                    acc[i][j] += a[i] * b[j];
        }
    }
#pragma unroll
    for (int j = 0; j < 8; ++j) {
        double bj = (double)b1[n0 + ty + 16 * j];
#pragma unroll
        for (int i = 0; i < 8; ++i) {
            m1out[(size_t)(m0 + tx + 16 * i) * H1_ + (n0 + ty + 16 * j)] =
                acc[i][j] + bj;
        }
    }
}

// ---------------------------------------------------------------------------
// Persistent per-sample SNN v4. Register state (m1[8t+q], m2[4t+q]).
// Byte-offset index lists + 8-deep gathers (as R6). NEW:
//  - single-barrier fast path for spike-free steps (speculative s2 flags)
//  - sparse epilogue over columns with cnt>0 only (exact: zero terms are
//    f64-neutral; nonzero count is ~0-3 so order-invariant).
// All arithmetic values/orders on the spiking path identical to R6.
// ---------------------------------------------------------------------------
__global__ __launch_bounds__(256) void k_snn(const double* __restrict__ m1_0,
                                             const float* __restrict__ b1,
                                             const float* __restrict__ W1T,  // [H2 idx][H1_] (8 KB cols)
                                             const float* __restrict__ W2T,  // [H1 idx][H2_] (4 KB cols)
                                             const float* __restrict__ b2,
                                             const float* __restrict__ Wo,   // [C_][H2_]
                                             const float* __restrict__ bo,
                                             const int* __restrict__ nsteps_p,
                                             float* __restrict__ out) {
    __shared__ __align__(16) double pjbuf[H2_];      // 8 KB; aliased as l1idx
    __shared__ __align__(16) int l2idx[H2_];         // 4 KB
    __shared__ unsigned long long s1by[32];          // 256 B: byte tid = s1 flags
    __shared__ unsigned long long s2nb[32];          // 256 B: nibble per thread
    __shared__ int ncnt[2];
    __shared__ int anyb1[4], anyb2[4];

    int* l1idx = (int*)pjbuf;                        // union with epilogue buffer

    int b = blockIdx.x;
    int tid = threadIdx.x;
    int lane = tid & 63;
    int wv = tid >> 6;
    int T = nsteps_p[0];

    double m1r[8], m2r[4];
    float b1f[8], b2f[4];
    int cnt[4];

    const double* m1p = m1_0 + (size_t)b * H1_ + 8 * tid;
    {
        double2 v0 = *(const double2*)(m1p + 0);
        double2 v1 = *(const double2*)(m1p + 2);
        double2 v2 = *(const double2*)(m1p + 4);
        double2 v3 = *(const double2*)(m1p + 6);
        m1r[0] = v0.x; m1r[1] = v0.y; m1r[2] = v1.x; m1r[3] = v1.y;
        m1r[4] = v2.x; m1r[5] = v2.y; m1r[6] = v3.x; m1r[7] = v3.y;
    }
    {
        float4 f0 = *(const float4*)(b1 + 8 * tid);
        float4 f1 = *(const float4*)(b1 + 8 * tid + 4);
        b1f[0] = f0.x; b1f[1] = f0.y; b1f[2] = f0.z; b1f[3] = f0.w;
        b1f[4] = f1.x; b1f[5] = f1.y; b1f[6] = f1.z; b1f[7] = f1.w;
        float4 f2 = *(const float4*)(b2 + 4 * tid);
        b2f[0] = f2.x; b2f[1] = f2.y; b2f[2] = f2.z; b2f[3] = f2.w;
    }
#pragma unroll
    for (int q = 0; q < 4; ++q) { m2r[q] = 0.0; cnt[q] = 0; }

    int anyS2 = 0;   // carried: any layer-2 spikes from previous step

#define ACC2(v) { m2r[0] += (double)(v).x; m2r[1] += (double)(v).y; \
                  m2r[2] += (double)(v).z; m2r[3] += (double)(v).w; }

    for (int t = 0; t < T; ++t) {
        if (t > 0) {
            // ---- layer 1: m1 = 0.9*m1_old - r1(m1_old) + b1 + W1 @ s2_prev ----
#pragma unroll
            for (int q = 0; q < 8; ++q)
                m1r[q] = 0.9 * m1r[q] - (m1r[q] > 1.0 ? 1.0 : 0.0) + (double)b1f[q];
            if (anyS2) {
                int n2 = ncnt[1];
                const char* Wc = (const char*)W1T;
                size_t toff = (size_t)tid << 5;            // tid*32 bytes (2 float4)
                for (int k2 = 0; k2 < n2; ++k2) {
                    const float4* c4 = (const float4*)(Wc + l2idx[k2] + toff);
                    float4 va = c4[0];
                    float4 vb = c4[1];
                    m1r[0] += (double)va.x; m1r[1] += (double)va.y;
                    m1r[2] += (double)va.z; m1r[3] += (double)va.w;
                    m1r[4] += (double)vb.x; m1r[5] += (double)vb.y;
                    m1r[6] += (double)vb.z; m1r[7] += (double)vb.w;
                }
            }
        }
        // ---- s1 flags -> byte tid ----
        unsigned bflag = 0;
#pragma unroll
        for (int q = 0; q < 8; ++q) bflag |= (m1r[q] > 1.0 ? 1u : 0u) << q;
        ((unsigned char*)s1by)[tid] = (unsigned char)bflag;
        {
            int wa = __any((int)bflag);
            if (lane == 0) anyb1[wv] = wa;
        }
        // ---- layer 2 decay + bias (uses OLD m2) ----
#pragma unroll
        for (int q = 0; q < 4; ++q)
            m2r[q] = 0.9 * m2r[q] - (m2r[q] > 1.0 ? 1.0 : 0.0) + (double)b2f[q];
        // ---- speculative s2 flags (final iff no s1 spikes this step) ----
        {
            unsigned nib = 0;
#pragma unroll
            for (int q = 0; q < 4; ++q) nib |= (m2r[q] > 1.0 ? 1u : 0u) << q;
            ((unsigned char*)s2nb)[tid] = (unsigned char)nib;
            int wa = __any((int)nib);
            if (lane == 0) anyb2[wv] = wa;
        }
        __syncthreads();                                   // A
        int any1 = anyb1[0] | anyb1[1] | anyb1[2] | anyb1[3];
        if (any1) {
            // ---- wave 0: expand s1 mask -> l1idx (ascending byte offsets) ----
            if (tid < 64) {
                unsigned long long bits = (tid < 32) ? s1by[tid] : 0ULL;
                int pc = __popcll(bits);
                int sc = pc;
#pragma unroll
                for (int d = 1; d < 64; d <<= 1) {
                    int o = __shfl_up(sc, d);
                    if (tid >= d) sc += o;
                }
                if (tid == 63) ncnt[0] = sc;
                int off = sc - pc;
                int base = tid << 6;
                while (bits) {
                    l1idx[off++] = (base + __builtin_ctzll(bits)) << 12;  // *4096 B
                    bits &= bits - 1;
                }
            }
            __syncthreads();                               // B
            // ---- layer-2 gather: 8-deep register-batched float4 ----
            {
                int n1 = ncnt[0];
                const char* Wc = (const char*)W2T;
                size_t toff = (size_t)tid << 4;            // tid*16 bytes
                int k = 0;
                for (; k + 8 <= n1; k += 8) {
                    int4 oa = *(const int4*)&l1idx[k];
                    int4 ob = *(const int4*)&l1idx[k + 4];
                    float4 v0 = *(const float4*)(Wc + oa.x + toff);
                    float4 v1 = *(const float4*)(Wc + oa.y + toff);
                    float4 v2 = *(const float4*)(Wc + oa.z + toff);
                    float4 v3 = *(const float4*)(Wc + oa.w + toff);
                    float4 v4 = *(const float4*)(Wc + ob.x + toff);
                    float4 v5 = *(const float4*)(Wc + ob.y + toff);
                    float4 v6 = *(const float4*)(Wc + ob.z + toff);
                    float4 v7 = *(const float4*)(Wc + ob.w + toff);
                    ACC2(v0); ACC2(v1); ACC2(v2); ACC2(v3);
                    ACC2(v4); ACC2(v5); ACC2(v6); ACC2(v7);
                }
                for (; k < n1; ++k) {
                    float4 v = *(const float4*)(Wc + l1idx[k] + toff);
                    ACC2(v);
                }
            }
            // ---- real s2 flags (m2 changed by gather) ----
            {
                unsigned nib = 0;
#pragma unroll
                for (int q = 0; q < 4; ++q) nib |= (m2r[q] > 1.0 ? 1u : 0u) << q;
                ((unsigned char*)s2nb)[tid] = (unsigned char)nib;
                int wa = __any((int)nib);
                if (lane == 0) anyb2[wv] = wa;
            }
            __syncthreads();                               // C
        }
        anyS2 = anyb2[0] | anyb2[1] | anyb2[2] | anyb2[3];
        // ---- spike counts (final m2) ----
#pragma unroll
        for (int q = 0; q < 4; ++q) cnt[q] += (m2r[q] > 1.0) ? 1 : 0;
        if (anyS2) {
            // ---- wave 0: compact nibbles -> words, expand -> l2idx ----
            if (tid < 64) {
                unsigned long long wbits = 0ULL;
                if (tid < 16) {
                    unsigned long long w0 = s2nb[2 * tid];
                    unsigned long long w1 = s2nb[2 * tid + 1];
                    w0 &= 0x0F0F0F0F0F0F0F0FULL;
                    w0 = (w0 | (w0 >> 4)) & 0x00FF00FF00FF00FFULL;
                    w0 = (w0 | (w0 >> 8)) & 0x0000FFFF0000FFFFULL;
                    w0 = (w0 | (w0 >> 16)) & 0x00000000FFFFFFFFULL;
                    w1 &= 0x0F0F0F0F0F0F0F0FULL;
                    w1 = (w1 | (w1 >> 4)) & 0x00FF00FF00FF00FFULL;
                    w1 = (w1 | (w1 >> 8)) & 0x0000FFFF0000FFFFULL;
                    w1 = (w1 | (w1 >> 16)) & 0x00000000FFFFFFFFULL;
                    wbits = w0 | (w1 << 32);
                }
                int pc = __popcll(wbits);
                int sc = pc;
#pragma unroll
                for (int d = 1; d < 64; d <<= 1) {
                    int o = __shfl_up(sc, d);
                    if (tid >= d) sc += o;
                }
                if (tid == 63) ncnt[1] = sc;
                int off = sc - pc;
                int base = tid << 6;
                while (wbits) {
                    l2idx[off++] = (base + __builtin_ctzll(wbits)) << 13;  // *8192 B
                    wbits &= wbits - 1;
                }
            }
            __syncthreads();                               // D
        }
    }
#undef ACC2

    // ---- sparse epilogue: out[b][c] = bo[c] + sum_{j: cnt>0} (cnt[j]/T)*Wo[c][j]
    __syncthreads();
#pragma unroll
    for (int q = 0; q < 4; ++q)
        pjbuf[4 * tid + q] = (double)cnt[q] / (double)T;
    {
        unsigned nib = 0;
#pragma unroll
        for (int q = 0; q < 4; ++q) nib |= (cnt[q] > 0 ? 1u : 0u) << q;
        ((unsigned char*)s2nb)[tid] = (unsigned char)nib;
    }
    __syncthreads();
    if (tid < 64) {
        unsigned long long wbits = 0ULL;
        if (tid < 16) {
            unsigned long long w0 = s2nb[2 * tid];
            unsigned long long w1 = s2nb[2 * tid + 1];
            w0 &= 0x0F0F0F0F0F0F0F0FULL;
            w0 = (w0 | (w0 >> 4)) & 0x00FF00FF00FF00FFULL;
            w0 = (w0 | (w0 >> 8)) & 0x0000FFFF0000FFFFULL;
            w0 = (w0 | (w0 >> 16)) & 0x00000000FFFFFFFFULL;
            w1 &= 0x0F0F0F0F0F0F0F0FULL;
            w1 = (w1 | (w1 >> 4)) & 0x00FF00FF00FF00FFULL;
            w1 = (w1 | (w1 >> 8)) & 0x0000FFFF0000FFFFULL;
            w1 = (w1 | (w1 >> 16)) & 0x00000000FFFFFFFFULL;
            wbits = w0 | (w1 << 32);
        }
        int pc = __popcll(wbits);
        int sc = pc;
#pragma unroll
        for (int d = 1; d < 64; d <<= 1) {
            int o = __shfl_up(sc, d);
            if (tid >= d) sc += o;
        }
        if (tid == 63) ncnt[1] = sc;
        int off = sc - pc;
        int base = tid << 6;
        while (wbits) {
            l2idx[off++] = base + __builtin_ctzll(wbits);   // plain j index
            wbits &= wbits - 1;
        }
    }
    __syncthreads();
    if (tid < C_) {
        int c = tid;
        int na = ncnt[1];
        const float* worow = &Wo[(size_t)c * H2_];
        double acc = 0.0;
        for (int k = 0; k < na; ++k) {
            int j = l2idx[k];
            acc += pjbuf[j] * (double)worow[j];
        }
        out[(size_t)b * C_ + c] = (float)(acc + (double)bo[c]);
    }
}

// ---------------------------------------------------------------------------
extern "C" void kernel_launch(void* const* d_in, const int* in_sizes, int n_in,
                              void* d_out, int out_size, void* d_ws, size_t ws_size,
                              hipStream_t stream) {
    const float* x  = (const float*)d_in[0];   // [4096,1024]
    const float* W1 = (const float*)d_in[1];   // [2048,1024]
    const float* b1 = (const float*)d_in[2];   // [2048]
    const float* W2 = (const float*)d_in[3];   // [1024,2048]
    const float* b2 = (const float*)d_in[4];   // [1024]
    const float* Wo = (const float*)d_in[5];   // [64,1024]
    const float* bo = (const float*)d_in[6];   // [64]
    const int* nst  = (const int*)d_in[7];     // [1] = 20
    float* out = (float*)d_out;

    size_t off_m1   = 0;                                   // f64 [4096][2048]
    size_t off_w1t  = off_m1 + (size_t)B_ * H1_ * 8;
    size_t off_w2t  = off_w1t + (size_t)D_ * H1_ * 4;
    size_t off_flag = off_w2t + (size_t)H1_ * H2_ * 4;
    size_t need     = off_flag + 64;
    if (ws_size < need) return;

    double* m1ws = (double*)((char*)d_ws + off_m1);
    float*  W1T  = (float*)((char*)d_ws + off_w1t);
    float*  W2T  = (float*)((char*)d_ws + off_w2t);
    int*    flag = (int*)((char*)d_ws + off_flag);

    k_probe<<<1, 64, 0, stream>>>(flag);

    k_transpose<<<dim3(D_ / 32, H1_ / 32), dim3(32, 8), 0, stream>>>(W1, W1T, H1_, D_);
    k_transpose<<<dim3(H1_ / 32, H2_ / 32), dim3(32, 8), 0, stream>>>(W2, W2T, H2_, H1_);

    k_gemm_mfma<<<dim3(B_ / GBM, H1_ / GBN), 512, 0, stream>>>(x, W1, b1, m1ws, flag);
    k_gemm1<<<dim3(B_ / BM, H1_ / BN), 256, 0, stream>>>(x, W1, b1, m1ws, flag);

    k_snn<<<B_, 256, 0, stream>>>(m1ws, b1, W1T, W2T, b2, Wo, bo, nst, out);
}

// Round 8
// 440.475 us; speedup vs baseline: 3.3964x; 1.0136x over previous
//
#include <hip/hip_runtime.h>
#include <hip/hip_bf16.h>

// Sizes (fixed by the reference): B=4096, D=1024, H1=2048, H2=1024, C=64, T=20
#define B_   4096
#define D_   1024
#define H1_  2048
#define H2_  1024
#define C_   64

typedef double d4 __attribute__((ext_vector_type(4)));

#if defined(__has_builtin)
#  if __has_builtin(__builtin_amdgcn_mfma_f64_16x16x4f64)
#    define MFMA64(A, B, C) __builtin_amdgcn_mfma_f64_16x16x4f64((A), (B), (C), 0, 0, 0)
#    define HAVE_MFMA64 1
#  elif __has_builtin(__builtin_amdgcn_mfma_f64_16x16x4_f64)
#    define MFMA64(A, B, C) __builtin_amdgcn_mfma_f64_16x16x4_f64((A), (B), (C), 0, 0, 0)
#    define HAVE_MFMA64 1
#  endif
#endif

// ---------------------------------------------------------------------------
// Probe: discover v_mfma_f64_16x16x4 D-fragment layout at runtime.
// ---------------------------------------------------------------------------
__global__ void k_probe(int* flag) {
#if defined(HAVE_MFMA64)
    int lane = threadIdx.x & 63;
    int lr = lane & 15, lk = lane >> 4;
    double a  = (double)(5 * lr + 3 * lk + 1);    // A[r][k] = 5r+3k+1
    double bb = (double)(11 * lk + 2 * lr + 2);   // B[k][c] = 11k+2c+2
    d4 c = {0.0, 0.0, 0.0, 0.0};
    c = MFMA64(a, bb, c);
    int okm[4] = {1, 1, 1, 1};
#pragma unroll
    for (int j = 0; j < 4; ++j) {
        double e1 = 0, e2 = 0, e3 = 0, e4 = 0;
        for (int k = 0; k < 4; ++k) {
            e1 += (double)(5 * (4 * lk + j) + 3 * k + 1) * (double)(11 * k + 2 * lr + 2);
            e2 += (double)(5 * lr + 3 * k + 1) * (double)(11 * k + 2 * (4 * lk + j) + 2);
            e3 += (double)(5 * (lk + 4 * j) + 3 * k + 1) * (double)(11 * k + 2 * lr + 2);
            e4 += (double)(5 * lr + 3 * k + 1) * (double)(11 * k + 2 * (lk + 4 * j) + 2);
        }
        if (c[j] != e1) okm[0] = 0;
        if (c[j] != e2) okm[1] = 0;
        if (c[j] != e3) okm[2] = 0;
        if (c[j] != e4) okm[3] = 0;
    }
    int f = 0;
    for (int m = 3; m >= 0; --m) {
        unsigned long long all = __ballot(okm[m] != 0);
        if (all == ~0ULL) f = m + 1;
    }
    if (lane == 0) flag[0] = f;
#else
    if ((threadIdx.x & 63) == 0) flag[0] = 0;
#endif
}

// ---------------------------------------------------------------------------
// Transpose: out[c][r] = in[r][c]   (f32, 32x32 LDS tiles)
// ---------------------------------------------------------------------------
__global__ __launch_bounds__(256) void k_transpose(const float* __restrict__ in,
                                                   float* __restrict__ out,
                                                   int R, int C) {
    __shared__ float t[32][33];
    int c0 = blockIdx.x * 32;
    int r0 = blockIdx.y * 32;
    int lx = threadIdx.x;
    int ly = threadIdx.y;
#pragma unroll
    for (int q = 0; q < 4; ++q) {
        int rr = ly + 8 * q;
        t[rr][lx] = in[(size_t)(r0 + rr) * C + (c0 + lx)];
    }
    __syncthreads();
#pragma unroll
    for (int q = 0; q < 4; ++q) {
        int cc = ly + 8 * q;
        out[(size_t)(c0 + cc) * R + (r0 + lx)] = t[lx][cc];
    }
}

// ---------------------------------------------------------------------------
// f64 MFMA GEMM v3: as v2 but conflict-free LDS via two-level pad:
// row k at float offset k*136 + (k>>2)*8.
//  - writes: bank = (8g+8q+s)%32, g-groups {0,8,16,24} -> 2-way (free)
//  - reads:  bank = (C+8*lk+16i+lr)%32, lk-groups {0,8,16,24} -> 2-way (free)
// Arithmetic identical to v2 (absmax 0 preserved).
// ---------------------------------------------------------------------------
#define GBM 128
#define GBN 128
#define GBK 16
#define AIDXSZ 2208   // AIDX(15,127)+1 = 2192, rounded up
#define AIDX(k, r) ((k) * 136 + (((k) >> 2) << 3) + (r))
__global__ __launch_bounds__(512, 4) void k_gemm_mfma(const float* __restrict__ x,
                                                      const float* __restrict__ W1,
                                                      const float* __restrict__ b1,
                                                      double* __restrict__ m1out,
                                                      const int* __restrict__ flag) {
#if defined(HAVE_MFMA64)
    int fm = flag[0];
    if (fm < 1 || fm > 4) return;
    __shared__ float As[AIDXSZ];
    __shared__ float Bs[AIDXSZ];

    int tid = threadIdx.x;
    int m0 = blockIdx.x * GBM;
    int n0 = blockIdx.y * GBN;
    int w = tid >> 6, lane = tid & 63;
    int wr = w >> 2;
    int wc = w & 3;
    int lr = lane & 15, lk = lane >> 4;
    int srow = tid >> 2;
    int g    = tid & 3;
    int skq  = g * 4;
    int sbase = AIDX(skq, srow);          // = 552*g + srow

    d4 acc[4][2];
#pragma unroll
    for (int i = 0; i < 4; ++i)
#pragma unroll
        for (int j = 0; j < 2; ++j) acc[i][j] = (d4){0.0, 0.0, 0.0, 0.0};

    for (int k0 = 0; k0 < D_; k0 += GBK) {
        float4 av = *(const float4*)&x [(size_t)(m0 + srow) * D_ + k0 + skq];
        float4 bv = *(const float4*)&W1[(size_t)(n0 + srow) * D_ + k0 + skq];
        __syncthreads();
        As[sbase + 0 * 136] = av.x;
        As[sbase + 1 * 136] = av.y;
        As[sbase + 2 * 136] = av.z;
        As[sbase + 3 * 136] = av.w;
        Bs[sbase + 0 * 136] = bv.x;
        Bs[sbase + 1 * 136] = bv.y;
        Bs[sbase + 2 * 136] = bv.z;
        Bs[sbase + 3 * 136] = bv.w;
        __syncthreads();
#pragma unroll
        for (int kb = 0; kb < 4; ++kb) {
            int abase = AIDX(kb * 4 + lk, wr * 64 + lr);
            int bbase = AIDX(kb * 4 + lk, wc * 32 + lr);
            double a[4], bfr[2];
#pragma unroll
            for (int i = 0; i < 4; ++i)
                a[i] = (double)As[abase + 16 * i];
#pragma unroll
            for (int j = 0; j < 2; ++j)
                bfr[j] = (double)Bs[bbase + 16 * j];
#pragma unroll
            for (int i = 0; i < 4; ++i)
#pragma unroll
                for (int j = 0; j < 2; ++j)
                    acc[i][j] = MFMA64(a[i], bfr[j], acc[i][j]);
        }
    }
#pragma unroll
    for (int j = 0; j < 2; ++j)
#pragma unroll
        for (int i = 0; i < 4; ++i)
#pragma unroll
            for (int r = 0; r < 4; ++r) {
                int rin = (fm == 1) ? (4 * lk + r) : (fm == 2) ? lr
                        : (fm == 3) ? (lk + 4 * r) : lr;
                int cin = (fm == 1) ? lr : (fm == 2) ? (4 * lk + r)
                        : (fm == 3) ? lr : (lk + 4 * r);
                int row = m0 + wr * 64 + 16 * i + rin;
                int col = n0 + wc * 32 + 16 * j + cin;
                m1out[(size_t)row * H1_ + col] = acc[i][j][r] + (double)b1[col];
            }
#else
    (void)x; (void)W1; (void)b1; (void)m1out; (void)flag;
#endif
}

// ---------------------------------------------------------------------------
// Fallback VALU f64 GEMM (proven). Runs iff flag not in {1..4}.
// ---------------------------------------------------------------------------
#define BM 128
#define BN 128
#define BK 8
__global__ __launch_bounds__(256) void k_gemm1(const float* __restrict__ x,
                                               const float* __restrict__ W1,
                                               const float* __restrict__ b1,
                                               double* __restrict__ m1out,
                                               const int* __restrict__ flag) {
    int fm = flag[0];
    if (fm >= 1 && fm <= 4) return;
    __shared__ double As[BK][BM + 4];
    __shared__ double Bs[BK][BN + 4];

    int tid = threadIdx.x;
    int m0 = blockIdx.x * BM;
    int n0 = blockIdx.y * BN;
    int tx = tid & 15;
    int ty = tid >> 4;
    int lr = tid >> 1;
    int lk = (tid & 1) * 4;

    double acc[8][8] = {};

    for (int k0 = 0; k0 < D_; k0 += BK) {
        float4 av = *(const float4*)&x [(size_t)(m0 + lr) * D_ + k0 + lk];
        float4 bv = *(const float4*)&W1[(size_t)(n0 + lr) * D_ + k0 + lk];
        __syncthreads();
        As[lk + 0][lr] = (double)av.x;
        As[lk + 1][lr] = (double)av.y;
        As[lk + 2][lr] = (double)av.z;
        As[lk + 3][lr] = (double)av.w;
        Bs[lk + 0][lr] = (double)bv.x;
        Bs[lk + 1][lr] = (double)bv.y;
        Bs[lk + 2][lr] = (double)bv.z;
        Bs[lk + 3][lr] = (double)bv.w;
        __syncthreads();
#pragma unroll
        for (int kk = 0; kk < BK; ++kk) {
            double a[8], b[8];
#pragma unroll
            for (int i = 0; i < 8; ++i) a[i] = As[kk][tx + 16 * i];
#pragma unroll
            for (int j = 0; j < 8; ++j) b[j] = Bs[kk][ty + 16 * j];
#pragma unroll
            for (int i = 0; i < 8; ++i)
#pragma unroll
                for (int j = 0; j < 8; ++j)
                    acc[i][j] += a[i] * b[j];
        }
    }
#pragma unroll
    for (int j = 0; j < 8; ++j) {
        double bj = (double)b1[n0 + ty + 16 * j];
#pragma unroll
        for (int i = 0; i < 8; ++i) {
            m1out[(size_t)(m0 + tx + 16 * i) * H1_ + (n0 + ty + 16 * j)] =
                acc[i][j] + bj;
        }
    }
}

// ---------------------------------------------------------------------------
// Persistent per-sample SNN v4 (unchanged from R7, ~135 µs).
// ---------------------------------------------------------------------------
__global__ __launch_bounds__(256) void k_snn(const double* __restrict__ m1_0,
                                             const float* __restrict__ b1,
                                             const float* __restrict__ W1T,
                                             const float* __restrict__ W2T,
                                             const float* __restrict__ b2,
                                             const float* __restrict__ Wo,
                                             const float* __restrict__ bo,
                                             const int* __restrict__ nsteps_p,
                                             float* __restrict__ out) {
    __shared__ __align__(16) double pjbuf[H2_];      // 8 KB; aliased as l1idx
    __shared__ __align__(16) int l2idx[H2_];         // 4 KB
    __shared__ unsigned long long s1by[32];          // 256 B
    __shared__ unsigned long long s2nb[32];          // 256 B
    __shared__ int ncnt[2];
    __shared__ int anyb1[4], anyb2[4];

    int* l1idx = (int*)pjbuf;

    int b = blockIdx.x;
    int tid = threadIdx.x;
    int lane = tid & 63;
    int wv = tid >> 6;
    int T = nsteps_p[0];

    double m1r[8], m2r[4];
    float b1f[8], b2f[4];
    int cnt[4];

    const double* m1p = m1_0 + (size_t)b * H1_ + 8 * tid;
    {
        double2 v0 = *(const double2*)(m1p + 0);
        double2 v1 = *(const double2*)(m1p + 2);
        double2 v2 = *(const double2*)(m1p + 4);
        double2 v3 = *(const double2*)(m1p + 6);
        m1r[0] = v0.x; m1r[1] = v0.y; m1r[2] = v1.x; m1r[3] = v1.y;
        m1r[4] = v2.x; m1r[5] = v2.y; m1r[6] = v3.x; m1r[7] = v3.y;
    }
    {
        float4 f0 = *(const float4*)(b1 + 8 * tid);
        float4 f1 = *(const float4*)(b1 + 8 * tid + 4);
        b1f[0] = f0.x; b1f[1] = f0.y; b1f[2] = f0.z; b1f[3] = f0.w;
        b1f[4] = f1.x; b1f[5] = f1.y; b1f[6] = f1.z; b1f[7] = f1.w;
        float4 f2 = *(const float4*)(b2 + 4 * tid);
        b2f[0] = f2.x; b2f[1] = f2.y; b2f[2] = f2.z; b2f[3] = f2.w;
    }
#pragma unroll
    for (int q = 0; q < 4; ++q) { m2r[q] = 0.0; cnt[q] = 0; }

    int anyS2 = 0;

#define ACC2(v) { m2r[0] += (double)(v).x; m2r[1] += (double)(v).y; \
                  m2r[2] += (double)(v).z; m2r[3] += (double)(v).w; }

    for (int t = 0; t < T; ++t) {
        if (t > 0) {
#pragma unroll
            for (int q = 0; q < 8; ++q)
                m1r[q] = 0.9 * m1r[q] - (m1r[q] > 1.0 ? 1.0 : 0.0) + (double)b1f[q];
            if (anyS2) {
                int n2 = ncnt[1];
                const char* Wc = (const char*)W1T;
                size_t toff = (size_t)tid << 5;
                for (int k2 = 0; k2 < n2; ++k2) {
                    const float4* c4 = (const float4*)(Wc + l2idx[k2] + toff);
                    float4 va = c4[0];
                    float4 vb = c4[1];
                    m1r[0] += (double)va.x; m1r[1] += (double)va.y;
                    m1r[2] += (double)va.z; m1r[3] += (double)va.w;
                    m1r[4] += (double)vb.x; m1r[5] += (double)vb.y;
                    m1r[6] += (double)vb.z; m1r[7] += (double)vb.w;
                }
            }
        }
        unsigned bflag = 0;
#pragma unroll
        for (int q = 0; q < 8; ++q) bflag |= (m1r[q] > 1.0 ? 1u : 0u) << q;
        ((unsigned char*)s1by)[tid] = (unsigned char)bflag;
        {
            int wa = __any((int)bflag);
            if (lane == 0) anyb1[wv] = wa;
        }
#pragma unroll
        for (int q = 0; q < 4; ++q)
            m2r[q] = 0.9 * m2r[q] - (m2r[q] > 1.0 ? 1.0 : 0.0) + (double)b2f[q];
        {
            unsigned nib = 0;
#pragma unroll
            for (int q = 0; q < 4; ++q) nib |= (m2r[q] > 1.0 ? 1u : 0u) << q;
            ((unsigned char*)s2nb)[tid] = (unsigned char)nib;
            int wa = __any((int)nib);
            if (lane == 0) anyb2[wv] = wa;
        }
        __syncthreads();                                   // A
        int any1 = anyb1[0] | anyb1[1] | anyb1[2] | anyb1[3];
        if (any1) {
            if (tid < 64) {
                unsigned long long bits = (tid < 32) ? s1by[tid] : 0ULL;
                int pc = __popcll(bits);
                int sc = pc;
#pragma unroll
                for (int d = 1; d < 64; d <<= 1) {
                    int o = __shfl_up(sc, d);
                    if (tid >= d) sc += o;
                }
                if (tid == 63) ncnt[0] = sc;
                int off = sc - pc;
                int base = tid << 6;
                while (bits) {
                    l1idx[off++] = (base + __builtin_ctzll(bits)) << 12;
                    bits &= bits - 1;
                }
            }
            __syncthreads();                               // B
            {
                int n1 = ncnt[0];
                const char* Wc = (const char*)W2T;
                size_t toff = (size_t)tid << 4;
                int k = 0;
                for (; k + 8 <= n1; k += 8) {
                    int4 oa = *(const int4*)&l1idx[k];
                    int4 ob = *(const int4*)&l1idx[k + 4];
                    float4 v0 = *(const float4*)(Wc + oa.x + toff);
                    float4 v1 = *(const float4*)(Wc + oa.y + toff);
                    float4 v2 = *(const float4*)(Wc + oa.z + toff);
                    float4 v3 = *(const float4*)(Wc + oa.w + toff);
                    float4 v4 = *(const float4*)(Wc + ob.x + toff);
                    float4 v5 = *(const float4*)(Wc + ob.y + toff);
                    float4 v6 = *(const float4*)(Wc + ob.z + toff);
                    float4 v7 = *(const float4*)(Wc + ob.w + toff);
                    ACC2(v0); ACC2(v1); ACC2(v2); ACC2(v3);
                    ACC2(v4); ACC2(v5); ACC2(v6); ACC2(v7);
                }
                for (; k < n1; ++k) {
                    float4 v = *(const float4*)(Wc + l1idx[k] + toff);
                    ACC2(v);
                }
            }
            {
                unsigned nib = 0;
#pragma unroll
                for (int q = 0; q < 4; ++q) nib |= (m2r[q] > 1.0 ? 1u : 0u) << q;
                ((unsigned char*)s2nb)[tid] = (unsigned char)nib;
                int wa = __any((int)nib);
                if (lane == 0) anyb2[wv] = wa;
            }
            __syncthreads();                               // C
        }
        anyS2 = anyb2[0] | anyb2[1] | anyb2[2] | anyb2[3];
#pragma unroll
        for (int q = 0; q < 4; ++q) cnt[q] += (m2r[q] > 1.0) ? 1 : 0;
        if (anyS2) {
            if (tid < 64) {
                unsigned long long wbits = 0ULL;
                if (tid < 16) {
                    unsigned long long w0 = s2nb[2 * tid];
                    unsigned long long w1 = s2nb[2 * tid + 1];
                    w0 &= 0x0F0F0F0F0F0F0F0FULL;
                    w0 = (w0 | (w0 >> 4)) & 0x00FF00FF00FF00FFULL;
                    w0 = (w0 | (w0 >> 8)) & 0x0000FFFF0000FFFFULL;
                    w0 = (w0 | (w0 >> 16)) & 0x00000000FFFFFFFFULL;
                    w1 &= 0x0F0F0F0F0F0F0F0FULL;
                    w1 = (w1 | (w1 >> 4)) & 0x00FF00FF00FF00FFULL;
                    w1 = (w1 | (w1 >> 8)) & 0x0000FFFF0000FFFFULL;
                    w1 = (w1 | (w1 >> 16)) & 0x00000000FFFFFFFFULL;
                    wbits = w0 | (w1 << 32);
                }
                int pc = __popcll(wbits);
                int sc = pc;
#pragma unroll
                for (int d = 1; d < 64; d <<= 1) {
                    int o = __shfl_up(sc, d);
                    if (tid >= d) sc += o;
                }
                if (tid == 63) ncnt[1] = sc;
                int off = sc - pc;
                int base = tid << 6;
                while (wbits) {
                    l2idx[off++] = (base + __builtin_ctzll(wbits)) << 13;
                    wbits &= wbits - 1;
                }
            }
            __syncthreads();                               // D
        }
    }
#undef ACC2

    // ---- sparse epilogue ----
    __syncthreads();
#pragma unroll
    for (int q = 0; q < 4; ++q)
        pjbuf[4 * tid + q] = (double)cnt[q] / (double)T;
    {
        unsigned nib = 0;
#pragma unroll
        for (int q = 0; q < 4; ++q) nib |= (cnt[q] > 0 ? 1u : 0u) << q;
        ((unsigned char*)s2nb)[tid] = (unsigned char)nib;
    }
    __syncthreads();
    if (tid < 64) {
        unsigned long long wbits = 0ULL;
        if (tid < 16) {
            unsigned long long w0 = s2nb[2 * tid];
            unsigned long long w1 = s2nb[2 * tid + 1];
            w0 &= 0x0F0F0F0F0F0F0F0FULL;
            w0 = (w0 | (w0 >> 4)) & 0x00FF00FF00FF00FFULL;
            w0 = (w0 | (w0 >> 8)) & 0x0000FFFF0000FFFFULL;
            w0 = (w0 | (w0 >> 16)) & 0x00000000FFFFFFFFULL;
            w1 &= 0x0F0F0F0F0F0F0F0FULL;
            w1 = (w1 | (w1 >> 4)) & 0x00FF00FF00FF00FFULL;
            w1 = (w1 | (w1 >> 8)) & 0x0000FFFF0000FFFFULL;
            w1 = (w1 | (w1 >> 16)) & 0x00000000FFFFFFFFULL;
            wbits = w0 | (w1 << 32);
        }
        int pc = __popcll(wbits);
        int sc = pc;
#pragma unroll
        for (int d = 1; d < 64; d <<= 1) {
            int o = __shfl_up(sc, d);
            if (tid >= d) sc += o;
        }
        if (tid == 63) ncnt[1] = sc;
        int off = sc - pc;
        int base = tid << 6;
        while (wbits) {
            l2idx[off++] = base + __builtin_ctzll(wbits);
            wbits &= wbits - 1;
        }
    }
    __syncthreads();
    if (tid < C_) {
        int c = tid;
        int na = ncnt[1];
        const float* worow = &Wo[(size_t)c * H2_];
        double acc = 0.0;
        for (int k = 0; k < na; ++k) {
            int j = l2idx[k];
            acc += pjbuf[j] * (double)worow[j];
        }
        out[(size_t)b * C_ + c] = (float)(acc + (double)bo[c]);
    }
}

// ---------------------------------------------------------------------------
extern "C" void kernel_launch(void* const* d_in, const int* in_sizes, int n_in,
                              void* d_out, int out_size, void* d_ws, size_t ws_size,
                              hipStream_t stream) {
    const float* x  = (const float*)d_in[0];   // [4096,1024]
    const float* W1 = (const float*)d_in[1];   // [2048,1024]
    const float* b1 = (const float*)d_in[2];   // [2048]
    const float* W2 = (const float*)d_in[3];   // [1024,2048]
    const float* b2 = (const float*)d_in[4];   // [1024]
    const float* Wo = (const float*)d_in[5];   // [64,1024]
    const float* bo = (const float*)d_in[6];   // [64]
    const int* nst  = (const int*)d_in[7];     // [1] = 20
    float* out = (float*)d_out;

    size_t off_m1   = 0;                                   // f64 [4096][2048]
    size_t off_w1t  = off_m1 + (size_t)B_ * H1_ * 8;
    size_t off_w2t  = off_w1t + (size_t)D_ * H1_ * 4;
    size_t off_flag = off_w2t + (size_t)H1_ * H2_ * 4;
    size_t need     = off_flag + 64;
    if (ws_size < need) return;

    double* m1ws = (double*)((char*)d_ws + off_m1);
    float*  W1T  = (float*)((char*)d_ws + off_w1t);
    float*  W2T  = (float*)((char*)d_ws + off_w2t);
    int*    flag = (int*)((char*)d_ws + off_flag);

    k_probe<<<1, 64, 0, stream>>>(flag);

    k_transpose<<<dim3(D_ / 32, H1_ / 32), dim3(32, 8), 0, stream>>>(W1, W1T, H1_, D_);
    k_transpose<<<dim3(H1_ / 32, H2_ / 32), dim3(32, 8), 0, stream>>>(W2, W2T, H2_, H1_);

    k_gemm_mfma<<<dim3(B_ / GBM, H1_ / GBN), 512, 0, stream>>>(x, W1, b1, m1ws, flag);
    k_gemm1<<<dim3(B_ / BM, H1_ / BN), 256, 0, stream>>>(x, W1, b1, m1ws, flag);

    k_snn<<<B_, 256, 0, stream>>>(m1ws, b1, W1T, W2T, b2, Wo, bo, nst, out);
}